// Round 6
// baseline (1009.797 us; speedup 1.0000x reference)
//
#include <hip/hip_runtime.h>
#include <hip/hip_bf16.h>
#include <math.h>

#define BB 4
#define TT 512
#define SDIM 64
#define ADIM 32
#define HDIM 512
#define NH 8
#define NBLK 6
#define DFF 2048
#define SS 1536          // 3*T
#define DH 64
#define MS (BB*SS)       // 6144 rows
#define SZE ((size_t)MS * HDIM)   // elements in one [MS][HDIM] partial

typedef __attribute__((ext_vector_type(8))) __bf16 bf16x8;
typedef __attribute__((ext_vector_type(4))) float f32x4;

__device__ __forceinline__ __bf16 f2b(float x) { return (__bf16)x; }

// async global->LDS, 16 B per lane; LDS dest = wave-uniform base + lane*16
__device__ __forceinline__ void gll16(const void* g, void* l) {
    __builtin_amdgcn_global_load_lds(
        (const __attribute__((address_space(1))) unsigned int*)g,
        (__attribute__((address_space(3))) unsigned int*)l, 16, 0, 0);
}

template<int N> __device__ __forceinline__ void vmwait() {
    if constexpr (N == 0) asm volatile("s_waitcnt vmcnt(0)" ::: "memory");
    else if constexpr (N == 3) asm volatile("s_waitcnt vmcnt(3)" ::: "memory");
    else if constexpr (N == 4) asm volatile("s_waitcnt vmcnt(4)" ::: "memory");
    else if constexpr (N == 6) asm volatile("s_waitcnt vmcnt(6)" ::: "memory");
    else if constexpr (N == 8) asm volatile("s_waitcnt vmcnt(8)" ::: "memory");
}
__device__ __forceinline__ void lgkm0() {
    asm volatile("s_waitcnt lgkmcnt(0)" ::: "memory");
}

// ================= embed + LN -> h_bf (bf16 residual stream) =================
// 8 rows of the SAME type per block: W read once from L2 per 8 rows.
// grid (64, 3, 4): chunk, type t, batch b. 512 threads.
__global__ __launch_bounds__(512) void embed_ln_kernel(
    const int* __restrict__ timesteps,
    const float* __restrict__ state0, const float* __restrict__ state1,
    const float* __restrict__ actions, const float* __restrict__ time_emb,
    const float* __restrict__ Ws, const float* __restrict__ bs,
    const float* __restrict__ Wa, const float* __restrict__ ba,
    const float* __restrict__ eg, const float* __restrict__ eb,
    __bf16* __restrict__ h_bf)
{
    __shared__ float xs[8][64];
    __shared__ float acc_s[8][512];
    __shared__ int tss[8];
    int c = blockIdx.x, t = blockIdx.y, b = blockIdx.z;
    int i0 = c * 8;
    int tid = threadIdx.x;
    int K = (t == 2) ? ADIM : SDIM;
    int ksh = (t == 2) ? 5 : 6;
    const float* W    = (t == 2) ? Wa : Ws;
    const float* bias = (t == 2) ? ba : bs;
    const float* src  = (t == 0) ? state0  + ((size_t)(b*TT + i0)) * SDIM
                      : (t == 1) ? state1  + ((size_t)(b*TT + i0)) * SDIM
                                 : actions + ((size_t)(b*TT + i0)) * ADIM;

    if (tid < 8) tss[tid] = timesteps[b*TT + i0 + tid];
    for (int idx = tid; idx < 8 * K; idx += 512) {
        int r = idx >> ksh, kk = idx & (K - 1);
        xs[r][kk] = src[r * K + kk];           // row stride == K, contiguous
    }
    __syncthreads();

    float acc[8];
    #pragma unroll
    for (int r = 0; r < 8; ++r)
        acc[r] = bias[tid] + time_emb[(size_t)tss[r] * HDIM + tid];
    for (int kk = 0; kk < K; ++kk) {
        float w = W[(size_t)kk * HDIM + tid];
        #pragma unroll
        for (int r = 0; r < 8; ++r) acc[r] += xs[r][kk] * w;
    }
    #pragma unroll
    for (int r = 0; r < 8; ++r) acc_s[r][tid] = acc[r];
    __syncthreads();

    // wave w owns row w: vector read, shuffle-only LN, 16B store
    int w = tid >> 6, lane = tid & 63;
    float4 p0 = *(const float4*)&acc_s[w][lane * 8];
    float4 p1 = *(const float4*)&acc_s[w][lane * 8 + 4];
    float v[8] = {p0.x, p0.y, p0.z, p0.w, p1.x, p1.y, p1.z, p1.w};
    float s = 0.f, sq = 0.f;
    #pragma unroll
    for (int u = 0; u < 8; ++u) { s += v[u]; sq += v[u] * v[u]; }
    #pragma unroll
    for (int off = 1; off < 64; off <<= 1) { s += __shfl_xor(s, off); sq += __shfl_xor(sq, off); }
    float mean = s * (1.f / HDIM);
    float var  = sq * (1.f / HDIM) - mean * mean;
    float inv  = rsqrtf(var + 1e-5f);
    float4 g0 = *(const float4*)(eg + lane * 8), g1 = *(const float4*)(eg + lane * 8 + 4);
    float4 b0 = *(const float4*)(eb + lane * 8), b1 = *(const float4*)(eb + lane * 8 + 4);
    float gg[8] = {g0.x, g0.y, g0.z, g0.w, g1.x, g1.y, g1.z, g1.w};
    float bbv[8] = {b0.x, b0.y, b0.z, b0.w, b1.x, b1.y, b1.z, b1.w};
    __bf16 o8[8];
    #pragma unroll
    for (int u = 0; u < 8; ++u) o8[u] = f2b((v[u] - mean) * inv * gg[u] + bbv[u]);
    int row = b * SS + (i0 + w) * 3 + t;
    *(uint4*)(h_bf + (size_t)row * HDIM + lane * 8) = *(uint4*)o8;
}

// ================= residual add (NP bf16 partials, SZE-strided) + LN =================
// wave-per-row: bf16x8 loads, shuffle-only reduction, no barriers.
// grid MS/4 = 1536 blocks x 256 threads.
template<int NP>
__global__ __launch_bounds__(256) void ln_add_kernel(
    __bf16* __restrict__ h_bf, const __bf16* __restrict__ parts,
    const float* __restrict__ g, const float* __restrict__ bvec)
{
    int w = threadIdx.x >> 6, lane = threadIdx.x & 63;
    int row = blockIdx.x * 4 + w;
    size_t base = (size_t)row * HDIM + lane * 8;
    bf16x8 h8 = *(const bf16x8*)(h_bf + base);
    bf16x8 p8[NP];
    #pragma unroll
    for (int p = 0; p < NP; ++p) p8[p] = *(const bf16x8*)(parts + p * SZE + base);
    float v[8], s = 0.f, sq = 0.f;
    #pragma unroll
    for (int u = 0; u < 8; ++u) {
        float acc = (float)h8[u];
        #pragma unroll
        for (int p = 0; p < NP; ++p) acc += (float)p8[p][u];
        v[u] = acc;
        s += acc; sq += acc * acc;
    }
    #pragma unroll
    for (int off = 1; off < 64; off <<= 1) { s += __shfl_xor(s, off); sq += __shfl_xor(sq, off); }
    float mean = s * (1.f / HDIM);
    float var  = sq * (1.f / HDIM) - mean * mean;
    float inv  = rsqrtf(var + 1e-5f);
    float4 g0 = *(const float4*)(g + lane * 8), g1 = *(const float4*)(g + lane * 8 + 4);
    float4 b0 = *(const float4*)(bvec + lane * 8), b1 = *(const float4*)(bvec + lane * 8 + 4);
    float gg[8] = {g0.x, g0.y, g0.z, g0.w, g1.x, g1.y, g1.z, g1.w};
    float bbv[8] = {b0.x, b0.y, b0.z, b0.w, b1.x, b1.y, b1.z, b1.w};
    __bf16 o8[8];
    #pragma unroll
    for (int u = 0; u < 8; ++u) o8[u] = f2b((v[u] - mean) * inv * gg[u] + bbv[u]);
    *(uint4*)(h_bf + base) = *(uint4*)o8;
}

// ================= weight pack: fp32 [K][N] -> bf16 [N][K], all 6 layers =================
// grid (769, 6): blockIdx.y = layer.
__global__ __launch_bounds__(256) void pack_kernel(
    const float* __restrict__ Wq, const float* __restrict__ Wk,
    const float* __restrict__ Wv, const float* __restrict__ Wo,
    const float* __restrict__ W1, const float* __restrict__ W2,
    const float* __restrict__ bq_, const float* __restrict__ bk_, const float* __restrict__ bv_,
    __bf16* __restrict__ wqkvT, __bf16* __restrict__ woT,
    __bf16* __restrict__ w1T, __bf16* __restrict__ w2T, float* __restrict__ biasq)
{
    int lyr = blockIdx.y;
    const float* wq = Wq + (size_t)lyr * HDIM * HDIM;
    const float* wk = Wk + (size_t)lyr * HDIM * HDIM;
    const float* wv = Wv + (size_t)lyr * HDIM * HDIM;
    const float* wo = Wo + (size_t)lyr * HDIM * HDIM;
    const float* w1 = W1 + (size_t)lyr * HDIM * DFF;
    const float* w2 = W2 + (size_t)lyr * DFF * HDIM;
    const float* bqL = bq_ + (size_t)lyr * HDIM;
    const float* bkL = bk_ + (size_t)lyr * HDIM;
    const float* bvL = bv_ + (size_t)lyr * HDIM;
    wqkvT += (size_t)lyr * 1536 * 512;
    woT   += (size_t)lyr * 512 * 512;
    w1T   += (size_t)lyr * 2048 * 512;
    w2T   += (size_t)lyr * 512 * 2048;
    biasq += (size_t)lyr * 1536;

    int bid = blockIdx.x;
    int tid = threadIdx.x;
    if (bid == 768) {
        for (int i = tid; i < 1536; i += 256)
            biasq[i] = (i < 512) ? bqL[i] : ((i < 1024) ? bkL[i-512] : bvL[i-1024]);
        return;
    }
    __shared__ float Ls[64][65];
    const float* src; __bf16* dst; int K, N, kt, nt;
    if (bid < 192) {
        int sec = bid / 64, t = bid % 64;
        src = (sec == 0) ? wq : (sec == 1) ? wk : wv;
        dst = wqkvT + (size_t)sec * 512 * 512;
        K = 512; N = 512; nt = t >> 3; kt = t & 7;
    } else if (bid < 256) {
        int t = bid - 192; src = wo; dst = woT; K = 512; N = 512; nt = t >> 3; kt = t & 7;
    } else if (bid < 512) {
        int t = bid - 256; src = w1; dst = w1T; K = 512; N = 2048; nt = t >> 3; kt = t & 7;
    } else {
        int t = bid - 512; src = w2; dst = w2T; K = 2048; N = 512; nt = t & 7; kt = t >> 3;
    }
    int k0 = kt * 64, n0 = nt * 64;
    int rr = tid >> 4, cc = (tid & 15) * 4;
    #pragma unroll
    for (int p = 0; p < 4; ++p) {
        float4 v = *(const float4*)(src + (size_t)(k0 + rr + p*16) * N + n0 + cc);
        Ls[rr + p*16][cc] = v.x; Ls[rr + p*16][cc+1] = v.y;
        Ls[rr + p*16][cc+2] = v.z; Ls[rr + p*16][cc+3] = v.w;
    }
    __syncthreads();
    int nn = tid >> 3, kc = (tid & 7) * 8;
    #pragma unroll
    for (int p = 0; p < 2; ++p) {
        __bf16 t8[8];
        #pragma unroll
        for (int t2 = 0; t2 < 8; ++t2) t8[t2] = f2b(Ls[kc + t2][nn + p*32]);
        *(uint4*)(dst + (size_t)(n0 + nn + p*32) * K + k0 + kc) = *(uint4*)t8;
    }
}

// ================= bf16 MFMA GEMM: 3-buffer depth-2 prefetch, counted vmcnt ======
// A: bf16 [M][lda].  Bt: bf16 [N][ldb].  C: bf16 [M][ldc].
// Split-K via blockIdx.z; bias applied only on z==0.
// VTMODE: blocks with n0 >= 1024 write their tile TRANSPOSED to VTout.
// K-loop: stage tile kt+2 -> vmcnt(2*LPS) -> s_barrier -> ds_read+MFMA ->
// lgkmcnt(0) -> s_barrier.  Loads get ~2 iterations to land (T3/T4).
template<int MT, bool VTMODE>
__global__ __launch_bounds__(256) void gemm_mfma(
    const __bf16* __restrict__ A, const __bf16* __restrict__ Bt,
    const float* __restrict__ bias, __bf16* __restrict__ C,
    __bf16* __restrict__ VTout,
    int N, int Ksub, int lda, int ldb, int ldc, int gelu, size_t cSplitStride)
{
    constexpr int MI = MT / 32;
    constexpr int LPS = MT/64 + 2;               // gll16 per wave per stage
    constexpr int SMB = 3*MT*64 + 3*128*64;      // 3 staging buffers
    __shared__ __align__(16) char sm[SMB];
    __bf16* As = (__bf16*)sm;                    // [3][MT][32]
    __bf16* Bs = (__bf16*)(sm + 3*MT*64);        // [3][128][32]
    int tid = threadIdx.x;
    int wave = tid >> 6, lane = tid & 63;
    int l15 = lane & 15, quad = lane >> 4;
    int wy = wave >> 1, wx = wave & 1;
    int m0 = blockIdx.y * MT, n0 = blockIdx.x * 128;
    int zs = blockIdx.z;
    int kbase = zs * Ksub;
    C += (size_t)zs * cSplitStride;

    int srow = lane >> 2;
    int clog = (lane & 3) ^ ((lane >> 3) & 3);
    int pchunk = (quad ^ ((l15 >> 1) & 3)) * 8;

    f32x4 acc[MI][4];
    #pragma unroll
    for (int i = 0; i < MI; ++i)
        #pragma unroll
        for (int j = 0; j < 4; ++j) acc[i][j] = (f32x4){0.f,0.f,0.f,0.f};

    const __bf16* Abase = A  + (size_t)m0 * lda + kbase + clog * 8;
    const __bf16* Bbase = Bt + (size_t)n0 * ldb + kbase + clog * 8;
    int NK = Ksub >> 5;

    auto STAGE = [&](int kt2, int b) {
        int k0 = kt2 << 5;
        #pragma unroll
        for (int q = 0; q < MT/64; ++q) {
            int r0 = (wave * (MT/64) + q) * 16;
            gll16(Abase + (size_t)(r0 + srow) * lda + k0, As + (b*MT + r0)*32);
        }
        #pragma unroll
        for (int q = 0; q < 2; ++q) {
            int r0 = (wave * 2 + q) * 16;
            gll16(Bbase + (size_t)(r0 + srow) * ldb + k0, Bs + (b*128 + r0)*32);
        }
    };

    // prologue: tiles 0,1 in flight
    STAGE(0, 0);
    STAGE(1, 1);

    int buf = 0;
    for (int kt = 0; kt < NK; ++kt) {
        int bnext = (buf == 2) ? 0 : buf + 1;        // (kt+1)%3
        int b2    = (bnext == 2) ? 0 : bnext + 1;    // (kt+2)%3
        if (kt + 2 < NK) { STAGE(kt + 2, b2); vmwait<2*LPS>(); }
        else if (kt + 1 < NK) { vmwait<LPS>(); }
        else { vmwait<0>(); }
        __builtin_amdgcn_s_barrier();        // tile kt fully landed (all waves)
        __builtin_amdgcn_sched_barrier(0);   // pin ds_reads below the barrier

        bf16x8 af[MI], bf[4];
        #pragma unroll
        for (int i = 0; i < MI; ++i)
            af[i] = *(const bf16x8*)&As[(buf*MT + wy*(MT/2) + i*16 + l15)*32 + pchunk];
        #pragma unroll
        for (int j = 0; j < 4; ++j)
            bf[j] = *(const bf16x8*)&Bs[(buf*128 + wx*64 + j*16 + l15)*32 + pchunk];
        #pragma unroll
        for (int i = 0; i < MI; ++i)
            #pragma unroll
            for (int j = 0; j < 4; ++j)
                acc[i][j] = __builtin_amdgcn_mfma_f32_16x16x32_bf16(af[i], bf[j], acc[i][j], 0, 0, 0);

        lgkm0();                             // all my LDS reads done
        __builtin_amdgcn_s_barrier();        // safe to overwrite buf (kt)%3 later
        buf = bnext;
    }

    if (VTMODE && n0 >= 1024) {
        // transpose tile (128 s x 128 d) into VT via LDS (reuse staging)
        __syncthreads();
        __bf16* T = (__bf16*)sm;          // logical [128 d][128 s], s-chunk swizzled
        #pragma unroll
        for (int j = 0; j < 4; ++j) {
            int dl = wx*64 + j*16 + l15;
            float bv = bias[n0 + dl];
            int x31 = dl & 31;
            #pragma unroll
            for (int i = 0; i < MI; ++i) {
                int sc = wy*16 + i*4 + quad;          // 4-elem s-chunk index
                int phys = sc ^ x31;
                __bf16 v4[4];
                #pragma unroll
                for (int r = 0; r < 4; ++r) v4[r] = f2b(acc[i][j][r] + bv);
                *(uint2*)(T + dl*128 + phys*4) = *(uint2*)v4;
            }
        }
        __syncthreads();
        int dl = tid >> 1, sh = (tid & 1) * 64;
        int dglob = n0 - 1024 + dl;
        int bb = m0 / SS, srel = m0 - bb*SS;
        __bf16* vb = VTout + ((size_t)(bb*NH + (dglob >> 6)) * 64 + (dglob & 63)) * SS + srel + sh;
        int x31 = dl & 31;
        #pragma unroll
        for (int u = 0; u < 8; ++u) {
            int c0 = (sh >> 2) + u*2;
            uint2 lo = *(const uint2*)(T + dl*128 + ((c0    ) ^ x31)*4);
            uint2 hi = *(const uint2*)(T + dl*128 + ((c0 + 1) ^ x31)*4);
            uint4 o; o.x = lo.x; o.y = lo.y; o.z = hi.x; o.w = hi.y;
            *(uint4*)(vb + u*8) = o;
        }
        return;
    }

    // ------- coalesced C-write via LDS restage (XOR-swizzled, no pad) -------
    __bf16* T = (__bf16*)sm;               // [MT][128], chunk ^= (row&7)
    #pragma unroll
    for (int j = 0; j < 4; ++j) {
        int cl = wx*64 + j*16 + l15;
        float bv = (zs == 0) ? bias[n0 + cl] : 0.f;
        #pragma unroll
        for (int i = 0; i < MI; ++i) {
            #pragma unroll
            for (int r = 0; r < 4; ++r) {
                int rr = wy*(MT/2) + i*16 + quad*4 + r;
                float v = acc[i][j][r] + bv;
                if (gelu) {
                    // tanh-form GELU via exp2+rcp (~7 VALU ops vs ~35 for erff)
                    float u2 = v * (0.7978845608f + 0.0356774081f * v * v);
                    float e  = __builtin_amdgcn_exp2f(u2 * 2.885390082f);  // exp(2u)
                    v = v * (1.f - __builtin_amdgcn_rcpf(e + 1.f));        // v*sigmoid(2u)
                }
                T[rr*128 + (cl ^ ((rr & 7) << 3))] = f2b(v);
            }
        }
    }
    __syncthreads();
    constexpr int TPR = 256 / MT;          // threads per output row (2 or 4)
    constexpr int CPT = 128 / TPR;         // cols per thread (64 or 32)
    int row = tid / TPR, cp = (tid % TPR) * CPT;
    __bf16* gout = C + (size_t)(m0 + row) * ldc + n0 + cp;
    #pragma unroll
    for (int u = 0; u < CPT/8; ++u) {      // 8 cols (16 B) per store
        int swc = ((cp >> 3) + u) ^ (row & 7);
        uint4 o = *(const uint4*)&T[row*128 + swc*8];
        *(uint4*)(gout + u*8) = o;
    }
}

// ================= S^T-layout MFMA flash attention, 64-row K-tiles =================
#define SM_C 0.18033688011112042f   // (1/8) * log2(e)

__device__ __forceinline__ unsigned pack2bf(float a, float b)
{
    union { __bf16 h[2]; unsigned u; } t;
    t.h[0] = (__bf16)a; t.h[1] = (__bf16)b;
    return t.u;
}

// P^T (two 16-row frags) -> PV B-frag. All shuffles at full wave exec,
// per-lane cndmask after (verified in rounds 4-10).
__device__ __forceinline__ bf16x8 ptrans(const float* p0, const float* p1, int lane)
{
    int l15 = lane & 15, quad = lane >> 4;
    unsigned pk0a = pack2bf(p0[0], p0[1]), pk0b = pack2bf(p0[2], p0[3]);
    unsigned pk1a = pack2bf(p1[0], p1[1]), pk1b = pack2bf(p1[2], p1[3]);
    int sA = l15 + (quad & 1) * 32;
    int sB = sA + 16;
    int hi = quad >> 1;
    unsigned a0A = (unsigned)__shfl((int)pk0a, sA);
    unsigned a1A = (unsigned)__shfl((int)pk1a, sA);
    unsigned b0A = (unsigned)__shfl((int)pk0b, sA);
    unsigned b1A = (unsigned)__shfl((int)pk1b, sA);
    unsigned a0B = (unsigned)__shfl((int)pk0a, sB);
    unsigned a1B = (unsigned)__shfl((int)pk1a, sB);
    unsigned b0B = (unsigned)__shfl((int)pk0b, sB);
    unsigned b1B = (unsigned)__shfl((int)pk1b, sB);
    union { unsigned u[4]; bf16x8 v; } pb;
    pb.u[0] = hi ? a1A : a0A;
    pb.u[1] = hi ? b1A : b0A;
    pb.u[2] = hi ? a1B : a0B;
    pb.u[3] = hi ? b1B : b0B;
    return pb.v;
}

// grid: 768 blocks (region-interleaved qt, LONGEST FIRST), 256 threads.
// qkc: [row][1024] = q|k; ctx overwrites the q-section (disjoint ownership).
// LDS (32 KB): K tile [64 s][64 d] x2 bufs, V^T tile [64 d][64 s] x2,
// chunk-swizzled phys = c ^ (row & 7). nkt = qt+1, uniform across waves.
// Counted-vmcnt double-barrier loop: next tile's loads stay in flight
// across the whole compute phase instead of being drained at the barrier.
__global__ __launch_bounds__(256, 3) void attn_kernel(
    __bf16* qkc, const __bf16* __restrict__ VT)
{
    __shared__ __align__(16) char smem[32768];

    int x = blockIdx.x;
    int region = x >> 8;          // 0,1,2
    int j = x & 255;
    int i = j >> 5;               // 0..7
    int hb = j & 31;
    // longest blocks dispatched first to shrink the tail
    int qt = (region == 0) ? (23 - i) : (region == 1) ? (8 + i) : i;
    int h = hb >> 2, b = hb & 3;

    int tid = threadIdx.x;
    int w = tid >> 6, lane = tid & 63;
    int l15 = lane & 15, quad = lane >> 4;
    int qrow0 = qt * 64 + w * 16;

    const __bf16* qp = qkc + (size_t)(b*SS + qrow0 + l15) * 1024 + h*64 + quad*8;
    bf16x8 qf0 = *(const bf16x8*)qp;
    bf16x8 qf1 = *(const bf16x8*)(qp + 32);

    // staging bases
    const __bf16* kgbase = qkc + (size_t)(b*SS) * 1024 + 512 + h*64;     // + srow*1024
    const __bf16* vgbase = VT + (size_t)(b*NH + h) * 64 * SS;            // + drow*SS
    int srow8 = lane >> 3;                        // 0..7
    int clog  = (lane & 7) ^ ((lane >> 3) & 7);   // logical chunk for DMA lane
    int sw0 = ((0*4 + quad) ^ (l15 & 7)) * 8;
    int sw1 = ((1*4 + quad) ^ (l15 & 7)) * 8;

    f32x4 o0 = {0.f,0.f,0.f,0.f}, o1 = o0, o2 = o0, o3 = o0;
    float sm_m = -1e30f, sm_l = 0.f;   // sm_l: PER-LANE partial (reduced at end)

    int nkt = qt + 1;

    auto STAGEA = [&](int jt2, int bufT) {
        int kb2 = jt2 * 64;
        __bf16* Kn = (__bf16*)(smem + bufT * 8192);
        __bf16* Vn = (__bf16*)(smem + 16384 + bufT * 8192);
        #pragma unroll
        for (int q = 0; q < 2; ++q) {
            int r0 = (w*2 + q) * 8;
            gll16(kgbase + (size_t)(kb2 + r0 + srow8) * 1024 + clog*8, Kn + r0*64);
            gll16(vgbase + (size_t)(r0 + srow8) * SS + kb2 + clog*8,   Vn + r0*64);
        }
    };

    STAGEA(0, 0);      // tile 0 in flight

    for (int jt = 0; jt < nkt; ++jt) {
        int buf = jt & 1;
        const __bf16* Kb = (const __bf16*)(smem + buf * 8192);
        const __bf16* Vb = (const __bf16*)(smem + 16384 + buf * 8192);
        if (jt + 1 < nkt) { STAGEA(jt + 1, buf ^ 1); vmwait<4>(); }
        else vmwait<0>();
        __builtin_amdgcn_s_barrier();        // tile jt landed for all waves
        __builtin_amdgcn_sched_barrier(0);

        f32x4 s[4];
        #pragma unroll
        for (int f = 0; f < 4; ++f) {
            bf16x8 k0 = *(const bf16x8*)(Kb + (16*f + l15)*64 + sw0);
            bf16x8 k1 = *(const bf16x8*)(Kb + (16*f + l15)*64 + sw1);
            f32x4 sf = {0.f,0.f,0.f,0.f};
            sf = __builtin_amdgcn_mfma_f32_16x16x32_bf16(k0, qf0, sf, 0, 0, 0);
            sf = __builtin_amdgcn_mfma_f32_16x16x32_bf16(k1, qf1, sf, 0, 0, 0);
            s[f] = sf;
        }
        int kb = jt * 64;

        if (kb + 63 > qrow0) {
            int qrow = qrow0 + l15;
            #pragma unroll
            for (int f = 0; f < 4; ++f)
                #pragma unroll
                for (int r = 0; r < 4; ++r)
                    if (kb + 16*f + quad*4 + r > qrow) s[f][r] = -1e30f;
        }

        // per-lane tree max (no cross-lane traffic on the common path)
        float tf[4];
        #pragma unroll
        for (int f = 0; f < 4; ++f)
            tf[f] = fmaxf(fmaxf(s[f][0], s[f][1]), fmaxf(s[f][2], s[f][3]));
        float tm_lane = fmaxf(fmaxf(tf[0], tf[1]), fmaxf(tf[2], tf[3]));

        // defer-max (T13): rescale only if some lane's max grows past
        // sm_m + 64 raw-score units (=> P <= e^8, safe in fp32/bf16).
        if (!__all(tm_lane <= sm_m + 64.f)) {
            float tm = tm_lane;
            tm = fmaxf(tm, __shfl_xor(tm, 16));
            tm = fmaxf(tm, __shfl_xor(tm, 32));
            float mnew = fmaxf(sm_m, tm);
            float alpha = __builtin_amdgcn_exp2f((sm_m - mnew) * SM_C);  // uniform
            sm_l *= alpha;
            o0 *= alpha; o1 *= alpha; o2 *= alpha; o3 *= alpha;
            sm_m = mnew;
        }

        // p = exp2(s*C - m*C): one fma + one exp2 per element
        float negmC = -sm_m * SM_C;
        float pp[4][4];
        float rf[4];
        #pragma unroll
        for (int f = 0; f < 4; ++f) {
            #pragma unroll
            for (int r = 0; r < 4; ++r)
                pp[f][r] = __builtin_amdgcn_exp2f(fmaf(s[f][r], SM_C, negmC));
            rf[f] = (pp[f][0] + pp[f][1]) + (pp[f][2] + pp[f][3]);
        }
        sm_l += (rf[0] + rf[1]) + (rf[2] + rf[3]);   // per-lane partial only

        bf16x8 pb01 = ptrans(pp[0], pp[1], lane);
        bf16x8 pb23 = ptrans(pp[2], pp[3], lane);

        #pragma unroll
        for (int ii = 0; ii < 4; ++ii) {
            bf16x8 va = *(const bf16x8*)(Vb + (16*ii + l15)*64 + sw0);
            bf16x8 vb = *(const bf16x8*)(Vb + (16*ii + l15)*64 + sw1);
            f32x4* op = (ii == 0) ? &o0 : (ii == 1) ? &o1 : (ii == 2) ? &o2 : &o3;
            *op = __builtin_amdgcn_mfma_f32_16x16x32_bf16(va, pb01, *op, 0, 0, 0);
            *op = __builtin_amdgcn_mfma_f32_16x16x32_bf16(vb, pb23, *op, 0, 0, 0);
        }

        lgkm0();                             // my reads (ds_read + bpermute) done
        __builtin_amdgcn_s_barrier();        // next iter may overwrite buf^1
    }

    // epilogue: reduce the deferred row-sum (lanes sharing l15), then
    // O^T regs -> LDS -> coalesced bf16 stores
    sm_l += __shfl_xor(sm_l, 16);
    sm_l += __shfl_xor(sm_l, 32);
    float* otw = (float*)smem + w * 16 * 68;
    float inv = 1.f / sm_l;
    #pragma unroll
    for (int r = 0; r < 4; ++r) {
        otw[l15*68 +  0 + quad*4 + r] = o0[r] * inv;
        otw[l15*68 + 16 + quad*4 + r] = o1[r] * inv;
        otw[l15*68 + 32 + quad*4 + r] = o2[r] * inv;
        otw[l15*68 + 48 + quad*4 + r] = o3[r] * inv;
    }
    lgkm0();
    int row = lane >> 2, ch = (lane & 3) * 16;
    union { __bf16 hh[16]; uint4 q4[2]; } ob;
    #pragma unroll
    for (int t2 = 0; t2 < 16; ++t2) ob.hh[t2] = f2b(otw[row*68 + ch + t2]);
    __bf16* cp = qkc + (size_t)(b*SS + qrow0 + row) * 1024 + h*64 + ch;
    *(uint4*)cp = ob.q4[0];
    *(uint4*)(cp + 8) = ob.q4[1];
}

// ================= final projection (bf16 h) =================
__global__ __launch_bounds__(256) void proj_kernel(
    const __bf16* __restrict__ h_bf, const float* __restrict__ Wp,
    const float* __restrict__ bp, float* __restrict__ out)
{
    int rid = blockIdx.x * 8 + (threadIdx.x >> 5);
    int col = threadIdx.x & 31;
    int b = rid / TT, i = rid - b * TT;
    const __bf16* x = h_bf + ((size_t)(b*SS) + 3*i + 1) * HDIM;
    float acc = bp[col];
    for (int k8 = 0; k8 < HDIM/8; ++k8) {
        bf16x8 x8 = *(const bf16x8*)(x + k8*8);
        #pragma unroll
        for (int u = 0; u < 8; ++u)
            acc += (float)x8[u] * Wp[(k8*8 + u) * ADIM + col];
    }
    out[(size_t)rid * ADIM + col] = acc;
}

extern "C" void kernel_launch(void* const* d_in, const int* in_sizes, int n_in,
                              void* d_out, int out_size, void* d_ws, size_t ws_size,
                              hipStream_t stream)
{
    (void)in_sizes; (void)n_in; (void)out_size; (void)ws_size;
    const int*   timesteps = (const int*)  d_in[0];
    const float* state0    = (const float*)d_in[1];
    const float* state1    = (const float*)d_in[2];
    const float* actions   = (const float*)d_in[3];
    const float* time_emb  = (const float*)d_in[4];
    const float* Ws  = (const float*)d_in[5];
    const float* bs  = (const float*)d_in[6];
    const float* Wa  = (const float*)d_in[7];
    const float* ba  = (const float*)d_in[8];
    const float* Wq  = (const float*)d_in[9];
    const float* bq  = (const float*)d_in[10];
    const float* Wk  = (const float*)d_in[11];
    const float* bk  = (const float*)d_in[12];
    const float* Wv  = (const float*)d_in[13];
    const float* bv  = (const float*)d_in[14];
    const float* Wo  = (const float*)d_in[15];
    const float* bo  = (const float*)d_in[16];
    const float* W1  = (const float*)d_in[17];
    const float* b1  = (const float*)d_in[18];
    const float* W2  = (const float*)d_in[19];
    const float* b2  = (const float*)d_in[20];
    const float* ln1g = (const float*)d_in[21];
    const float* ln1b = (const float*)d_in[22];
    const float* ln2g = (const float*)d_in[23];
    const float* ln2b = (const float*)d_in[24];
    const float* elng = (const float*)d_in[25];
    const float* elnb = (const float*)d_in[26];
    const float* Wp   = (const float*)d_in[27];
    const float* bp   = (const float*)d_in[28];
    float* out = (float*)d_out;

    char* p = (char*)d_ws;
    __bf16* h_bf = (__bf16*)p;           p += SZE * 2;                  // residual (bf16)
    __bf16* qk   = (__bf16*)p;           p += (size_t)MS * 1024 * 2;   // q|k; q-sec doubles as ctx
    __bf16* VT   = (__bf16*)p;           p += SZE * 2;
    /* hid extension */                  p += SZE * 2;                  // hid = qk..VT..ext (MSx2048)
    __bf16* tmp  = (__bf16*)p;           p += SZE * 2 * 2;              // split-K partials 0..1
    __bf16* wqkvT = (__bf16*)p;          p += (size_t)NBLK * 1536 * 512 * 2;
    __bf16* woT   = (__bf16*)p;          p += (size_t)NBLK * 512 * 512 * 2;
    __bf16* w1T   = (__bf16*)p;          p += (size_t)NBLK * 2048 * 512 * 2;
    __bf16* w2T   = (__bf16*)p;          p += (size_t)NBLK * 512 * 2048 * 2;
    float*  biasq = (float*)p;           p += (size_t)NBLK * 1536 * 4;
    __bf16* hid   = qk;                  // MS x 2048 bf16 spans qk+VT+ext

    embed_ln_kernel<<<dim3(TT/8, 3, BB), 512, 0, stream>>>(timesteps, state0, state1, actions,
                                                           time_emb, Ws, bs, Wa, ba, elng, elnb, h_bf);

    // pack all 6 layers in one launch
    pack_kernel<<<dim3(769, NBLK), 256, 0, stream>>>(Wq, Wk, Wv, Wo, W1, W2, bq, bk, bv,
                                                     wqkvT, woT, w1T, w2T, biasq);

    dim3 gQKV(1536/128, MS/128, 1);    // 12 x 48
    dim3 gO  (512/128,  MS/64, 2);     // 4 x 96 x 2  (split-K=2, MT=64)
    dim3 gF1 (2048/128, MS/128, 1);    // 16 x 48

    for (int lyr = 0; lyr < NBLK; ++lyr) {
        const __bf16* wqkvT_l = wqkvT + (size_t)lyr * 1536 * 512;
        const __bf16* woT_l   = woT   + (size_t)lyr * 512 * 512;
        const __bf16* w1T_l   = w1T   + (size_t)lyr * 2048 * 512;
        const __bf16* w2T_l   = w2T   + (size_t)lyr * 512 * 2048;
        const float*  biasq_l = biasq + (size_t)lyr * 1536;

        // QKV: q|k rows -> qk (ldc 1024); V tiles transposed -> VT in-epilogue
        gemm_mfma<128, true><<<gQKV, 256, 0, stream>>>(h_bf, wqkvT_l, biasq_l, qk, VT,
                                                       1536, 512, 512, 512, 1024, 0, 0);
        attn_kernel<<<dim3(768), 256, 0, stream>>>(qk, VT);
        // WO: A = ctx (q-section, lda 1024); split-K=2 (256 each)
        gemm_mfma<64, false><<<gO, 256, 0, stream>>>(qk, woT_l, bo + lyr*HDIM, tmp, nullptr,
                                                     512, 256, 1024, 512, 512, 0, SZE);
        ln_add_kernel<2><<<MS/4, 256, 0, stream>>>(h_bf, tmp,
                                                   ln1g + lyr*HDIM, ln1b + lyr*HDIM);
        gemm_mfma<128, false><<<gF1, 256, 0, stream>>>(h_bf, w1T_l, b1 + lyr*DFF, hid, nullptr,
                                                       2048, 512, 512, 512, 2048, 1, 0);
        // W2: split-K=2 (1024 each), MT=64
        gemm_mfma<64, false><<<gO, 256, 0, stream>>>(hid, w2T_l, b2 + lyr*HDIM, tmp, nullptr,
                                                     512, 1024, 2048, 2048, 512, 0, SZE);
        ln_add_kernel<2><<<MS/4, 256, 0, stream>>>(h_bf, tmp,
                                                   ln2g + lyr*HDIM, ln2b + lyr*HDIM);
    }

    proj_kernel<<<(BB*TT)/8, 256, 0, stream>>>(h_bf, Wp, bp, out);
}

// Round 7
// 920.821 us; speedup vs baseline: 1.0966x; 1.0966x over previous
//
#include <hip/hip_runtime.h>
#include <hip/hip_bf16.h>
#include <math.h>

#define BB 4
#define TT 512
#define SDIM 64
#define ADIM 32
#define HDIM 512
#define NH 8
#define NBLK 6
#define DFF 2048
#define SS 1536          // 3*T
#define DH 64
#define MS (BB*SS)       // 6144 rows
#define SZE ((size_t)MS * HDIM)   // elements in one [MS][HDIM] partial

typedef __attribute__((ext_vector_type(8))) __bf16 bf16x8;
typedef __attribute__((ext_vector_type(4))) float f32x4;

__device__ __forceinline__ __bf16 f2b(float x) { return (__bf16)x; }

// async global->LDS, 16 B per lane; LDS dest = wave-uniform base + lane*16
__device__ __forceinline__ void gll16(const void* g, void* l) {
    __builtin_amdgcn_global_load_lds(
        (const __attribute__((address_space(1))) unsigned int*)g,
        (__attribute__((address_space(3))) unsigned int*)l, 16, 0, 0);
}

// ================= embed + LN -> h_bf (bf16 residual stream) =================
// 8 rows of the SAME type per block: W read once from L2 per 8 rows.
// grid (64, 3, 4): chunk, type t, batch b. 512 threads.
__global__ __launch_bounds__(512) void embed_ln_kernel(
    const int* __restrict__ timesteps,
    const float* __restrict__ state0, const float* __restrict__ state1,
    const float* __restrict__ actions, const float* __restrict__ time_emb,
    const float* __restrict__ Ws, const float* __restrict__ bs,
    const float* __restrict__ Wa, const float* __restrict__ ba,
    const float* __restrict__ eg, const float* __restrict__ eb,
    __bf16* __restrict__ h_bf)
{
    __shared__ float xs[8][64];
    __shared__ float acc_s[8][512];
    __shared__ int tss[8];
    int c = blockIdx.x, t = blockIdx.y, b = blockIdx.z;
    int i0 = c * 8;
    int tid = threadIdx.x;
    int K = (t == 2) ? ADIM : SDIM;
    int ksh = (t == 2) ? 5 : 6;
    const float* W    = (t == 2) ? Wa : Ws;
    const float* bias = (t == 2) ? ba : bs;
    const float* src  = (t == 0) ? state0  + ((size_t)(b*TT + i0)) * SDIM
                      : (t == 1) ? state1  + ((size_t)(b*TT + i0)) * SDIM
                                 : actions + ((size_t)(b*TT + i0)) * ADIM;

    if (tid < 8) tss[tid] = timesteps[b*TT + i0 + tid];
    for (int idx = tid; idx < 8 * K; idx += 512) {
        int r = idx >> ksh, kk = idx & (K - 1);
        xs[r][kk] = src[r * K + kk];           // row stride == K, contiguous
    }
    __syncthreads();

    float acc[8];
    #pragma unroll
    for (int r = 0; r < 8; ++r)
        acc[r] = bias[tid] + time_emb[(size_t)tss[r] * HDIM + tid];
    for (int kk = 0; kk < K; ++kk) {
        float w = W[(size_t)kk * HDIM + tid];
        #pragma unroll
        for (int r = 0; r < 8; ++r) acc[r] += xs[r][kk] * w;
    }
    #pragma unroll
    for (int r = 0; r < 8; ++r) acc_s[r][tid] = acc[r];
    __syncthreads();

    // wave w owns row w: vector read, shuffle-only LN, 16B store
    int w = tid >> 6, lane = tid & 63;
    float4 p0 = *(const float4*)&acc_s[w][lane * 8];
    float4 p1 = *(const float4*)&acc_s[w][lane * 8 + 4];
    float v[8] = {p0.x, p0.y, p0.z, p0.w, p1.x, p1.y, p1.z, p1.w};
    float s = 0.f, sq = 0.f;
    #pragma unroll
    for (int u = 0; u < 8; ++u) { s += v[u]; sq += v[u] * v[u]; }
    #pragma unroll
    for (int off = 1; off < 64; off <<= 1) { s += __shfl_xor(s, off); sq += __shfl_xor(sq, off); }
    float mean = s * (1.f / HDIM);
    float var  = sq * (1.f / HDIM) - mean * mean;
    float inv  = rsqrtf(var + 1e-5f);
    float4 g0 = *(const float4*)(eg + lane * 8), g1 = *(const float4*)(eg + lane * 8 + 4);
    float4 b0 = *(const float4*)(eb + lane * 8), b1 = *(const float4*)(eb + lane * 8 + 4);
    float gg[8] = {g0.x, g0.y, g0.z, g0.w, g1.x, g1.y, g1.z, g1.w};
    float bbv[8] = {b0.x, b0.y, b0.z, b0.w, b1.x, b1.y, b1.z, b1.w};
    __bf16 o8[8];
    #pragma unroll
    for (int u = 0; u < 8; ++u) o8[u] = f2b((v[u] - mean) * inv * gg[u] + bbv[u]);
    int row = b * SS + (i0 + w) * 3 + t;
    *(uint4*)(h_bf + (size_t)row * HDIM + lane * 8) = *(uint4*)o8;
}

// ================= residual add (NP bf16 partials, SZE-strided) + LN =================
// wave-per-row: bf16x8 loads, shuffle-only reduction, no barriers.
// grid MS/4 = 1536 blocks x 256 threads.
template<int NP>
__global__ __launch_bounds__(256) void ln_add_kernel(
    __bf16* __restrict__ h_bf, const __bf16* __restrict__ parts,
    const float* __restrict__ g, const float* __restrict__ bvec)
{
    int w = threadIdx.x >> 6, lane = threadIdx.x & 63;
    int row = blockIdx.x * 4 + w;
    size_t base = (size_t)row * HDIM + lane * 8;
    bf16x8 h8 = *(const bf16x8*)(h_bf + base);
    bf16x8 p8[NP];
    #pragma unroll
    for (int p = 0; p < NP; ++p) p8[p] = *(const bf16x8*)(parts + p * SZE + base);
    float v[8], s = 0.f, sq = 0.f;
    #pragma unroll
    for (int u = 0; u < 8; ++u) {
        float acc = (float)h8[u];
        #pragma unroll
        for (int p = 0; p < NP; ++p) acc += (float)p8[p][u];
        v[u] = acc;
        s += acc; sq += acc * acc;
    }
    #pragma unroll
    for (int off = 1; off < 64; off <<= 1) { s += __shfl_xor(s, off); sq += __shfl_xor(sq, off); }
    float mean = s * (1.f / HDIM);
    float var  = sq * (1.f / HDIM) - mean * mean;
    float inv  = rsqrtf(var + 1e-5f);
    float4 g0 = *(const float4*)(g + lane * 8), g1 = *(const float4*)(g + lane * 8 + 4);
    float4 b0 = *(const float4*)(bvec + lane * 8), b1 = *(const float4*)(bvec + lane * 8 + 4);
    float gg[8] = {g0.x, g0.y, g0.z, g0.w, g1.x, g1.y, g1.z, g1.w};
    float bbv[8] = {b0.x, b0.y, b0.z, b0.w, b1.x, b1.y, b1.z, b1.w};
    __bf16 o8[8];
    #pragma unroll
    for (int u = 0; u < 8; ++u) o8[u] = f2b((v[u] - mean) * inv * gg[u] + bbv[u]);
    *(uint4*)(h_bf + base) = *(uint4*)o8;
}

// ================= weight pack: fp32 [K][N] -> bf16 [N][K], all 6 layers =================
// grid (769, 6): blockIdx.y = layer.
__global__ __launch_bounds__(256) void pack_kernel(
    const float* __restrict__ Wq, const float* __restrict__ Wk,
    const float* __restrict__ Wv, const float* __restrict__ Wo,
    const float* __restrict__ W1, const float* __restrict__ W2,
    const float* __restrict__ bq_, const float* __restrict__ bk_, const float* __restrict__ bv_,
    __bf16* __restrict__ wqkvT, __bf16* __restrict__ woT,
    __bf16* __restrict__ w1T, __bf16* __restrict__ w2T, float* __restrict__ biasq)
{
    int lyr = blockIdx.y;
    const float* wq = Wq + (size_t)lyr * HDIM * HDIM;
    const float* wk = Wk + (size_t)lyr * HDIM * HDIM;
    const float* wv = Wv + (size_t)lyr * HDIM * HDIM;
    const float* wo = Wo + (size_t)lyr * HDIM * HDIM;
    const float* w1 = W1 + (size_t)lyr * HDIM * DFF;
    const float* w2 = W2 + (size_t)lyr * DFF * HDIM;
    const float* bqL = bq_ + (size_t)lyr * HDIM;
    const float* bkL = bk_ + (size_t)lyr * HDIM;
    const float* bvL = bv_ + (size_t)lyr * HDIM;
    wqkvT += (size_t)lyr * 1536 * 512;
    woT   += (size_t)lyr * 512 * 512;
    w1T   += (size_t)lyr * 2048 * 512;
    w2T   += (size_t)lyr * 512 * 2048;
    biasq += (size_t)lyr * 1536;

    int bid = blockIdx.x;
    int tid = threadIdx.x;
    if (bid == 768) {
        for (int i = tid; i < 1536; i += 256)
            biasq[i] = (i < 512) ? bqL[i] : ((i < 1024) ? bkL[i-512] : bvL[i-1024]);
        return;
    }
    __shared__ float Ls[64][65];
    const float* src; __bf16* dst; int K, N, kt, nt;
    if (bid < 192) {
        int sec = bid / 64, t = bid % 64;
        src = (sec == 0) ? wq : (sec == 1) ? wk : wv;
        dst = wqkvT + (size_t)sec * 512 * 512;
        K = 512; N = 512; nt = t >> 3; kt = t & 7;
    } else if (bid < 256) {
        int t = bid - 192; src = wo; dst = woT; K = 512; N = 512; nt = t >> 3; kt = t & 7;
    } else if (bid < 512) {
        int t = bid - 256; src = w1; dst = w1T; K = 512; N = 2048; nt = t >> 3; kt = t & 7;
    } else {
        int t = bid - 512; src = w2; dst = w2T; K = 2048; N = 512; nt = t & 7; kt = t >> 3;
    }
    int k0 = kt * 64, n0 = nt * 64;
    int rr = tid >> 4, cc = (tid & 15) * 4;
    #pragma unroll
    for (int p = 0; p < 4; ++p) {
        float4 v = *(const float4*)(src + (size_t)(k0 + rr + p*16) * N + n0 + cc);
        Ls[rr + p*16][cc] = v.x; Ls[rr + p*16][cc+1] = v.y;
        Ls[rr + p*16][cc+2] = v.z; Ls[rr + p*16][cc+3] = v.w;
    }
    __syncthreads();
    int nn = tid >> 3, kc = (tid & 7) * 8;
    #pragma unroll
    for (int p = 0; p < 2; ++p) {
        __bf16 t8[8];
        #pragma unroll
        for (int t2 = 0; t2 < 8; ++t2) t8[t2] = f2b(Ls[kc + t2][nn + p*32]);
        *(uint4*)(dst + (size_t)(n0 + nn + p*32) * K + k0 + kc) = *(uint4*)t8;
    }
}

// ================= bf16 MFMA GEMM, double-buffered async LDS staging =================
// Round-3 proven structure: 2 buffers, one __syncthreads per K-step,
// prefetch kt+1 inside the loop, direct C-write.
// A: bf16 [M][lda].  Bt: bf16 [N][ldb].  C: bf16 [M][ldc].
// Split-K via blockIdx.z; bias applied only on z==0.
// VTMODE: blocks with n0 >= 1024 write their tile TRANSPOSED to VTout
// (works for MT=64 and MT=128).
template<int MT, bool VTMODE>
__global__ __launch_bounds__(256) void gemm_mfma(
    const __bf16* __restrict__ A, const __bf16* __restrict__ Bt,
    const float* __restrict__ bias, __bf16* __restrict__ C,
    __bf16* __restrict__ VTout,
    int N, int Ksub, int lda, int ldb, int ldc, int gelu, size_t cSplitStride)
{
    constexpr int MI = MT / 32;
    constexpr int SMB = 2*MT*64 + 2*128*64;
    __shared__ __align__(16) char sm[SMB];
    __bf16* As = (__bf16*)sm;                    // [2][MT][32]
    __bf16* Bs = (__bf16*)(sm + 2*MT*64);        // [2][128][32]
    int tid = threadIdx.x;
    int wave = tid >> 6, lane = tid & 63;
    int l15 = lane & 15, quad = lane >> 4;
    int wy = wave >> 1, wx = wave & 1;
    int m0 = blockIdx.y * MT, n0 = blockIdx.x * 128;
    int zs = blockIdx.z;
    int kbase = zs * Ksub;
    C += (size_t)zs * cSplitStride;

    int srow = lane >> 2;
    int clog = (lane & 3) ^ ((lane >> 3) & 3);
    int pchunk = (quad ^ ((l15 >> 1) & 3)) * 8;

    f32x4 acc[MI][4];
    #pragma unroll
    for (int i = 0; i < MI; ++i)
        #pragma unroll
        for (int j = 0; j < 4; ++j) acc[i][j] = (f32x4){0.f,0.f,0.f,0.f};

    const __bf16* Abase = A  + (size_t)m0 * lda + kbase + clog * 8;
    const __bf16* Bbase = Bt + (size_t)n0 * ldb + kbase + clog * 8;
    int NK = Ksub >> 5;

    // prologue: stage k-tile 0 into buffer 0
    #pragma unroll
    for (int q = 0; q < MT/64; ++q) {
        int r0 = (wave * (MT/64) + q) * 16;
        gll16(Abase + (size_t)(r0 + srow) * lda, As + r0*32);
    }
    #pragma unroll
    for (int q = 0; q < 2; ++q) {
        int r0 = (wave * 2 + q) * 16;
        gll16(Bbase + (size_t)(r0 + srow) * ldb, Bs + r0*32);
    }

    for (int kt = 0; kt < NK; ++kt) {
        int buf = kt & 1;
        __syncthreads();   // drains the loads for `buf` (issued one full iter ago)
        if (kt + 1 < NK) {
            int k0 = (kt + 1) << 5;
            #pragma unroll
            for (int q = 0; q < MT/64; ++q) {
                int r0 = (wave * (MT/64) + q) * 16;
                gll16(Abase + (size_t)(r0 + srow) * lda + k0, As + ((buf^1)*MT + r0)*32);
            }
            #pragma unroll
            for (int q = 0; q < 2; ++q) {
                int r0 = (wave * 2 + q) * 16;
                gll16(Bbase + (size_t)(r0 + srow) * ldb + k0, Bs + ((buf^1)*128 + r0)*32);
            }
        }
        bf16x8 af[MI], bf[4];
        #pragma unroll
        for (int i = 0; i < MI; ++i)
            af[i] = *(const bf16x8*)&As[(buf*MT + wy*(MT/2) + i*16 + l15)*32 + pchunk];
        #pragma unroll
        for (int j = 0; j < 4; ++j)
            bf[j] = *(const bf16x8*)&Bs[(buf*128 + wx*64 + j*16 + l15)*32 + pchunk];
        #pragma unroll
        for (int i = 0; i < MI; ++i)
            #pragma unroll
            for (int j = 0; j < 4; ++j)
                acc[i][j] = __builtin_amdgcn_mfma_f32_16x16x32_bf16(af[i], bf[j], acc[i][j], 0, 0, 0);
    }

    if (VTMODE && n0 >= 1024) {
        // transpose tile (MT s x 128 d) into VT via LDS (reuse staging)
        constexpr int SCH = MT / 4;       // s-chunks of 4
        __syncthreads();
        __bf16* T = (__bf16*)sm;          // logical [128 d][MT s], s-chunk swizzled
        #pragma unroll
        for (int j = 0; j < 4; ++j) {
            int dl = wx*64 + j*16 + l15;
            float bv = bias[n0 + dl];
            int xm = dl & (SCH - 1);
            #pragma unroll
            for (int i = 0; i < MI; ++i) {
                int sc = wy*(MI*4) + i*4 + quad;      // 4-elem s-chunk index
                int phys = sc ^ xm;
                __bf16 v4[4];
                #pragma unroll
                for (int r = 0; r < 4; ++r) v4[r] = f2b(acc[i][j][r] + bv);
                *(uint2*)(T + dl*MT + phys*4) = *(uint2*)v4;
            }
        }
        __syncthreads();
        constexpr int SPT = MT / 2;       // s per thread (2 threads per d row)
        int dl = tid >> 1, sh = (tid & 1) * SPT;
        int dglob = n0 - 1024 + dl;
        int bb = m0 / SS, srel = m0 - bb*SS;
        __bf16* vb = VTout + ((size_t)(bb*NH + (dglob >> 6)) * 64 + (dglob & 63)) * SS + srel + sh;
        int xm = dl & (SCH - 1);
        #pragma unroll
        for (int u = 0; u < SPT/8; ++u) {
            int c0 = (sh >> 2) + u*2;
            uint2 lo = *(const uint2*)(T + dl*MT + ((c0    ) ^ xm)*4);
            uint2 hi = *(const uint2*)(T + dl*MT + ((c0 + 1) ^ xm)*4);
            uint4 o; o.x = lo.x; o.y = lo.y; o.z = hi.x; o.w = hi.y;
            *(uint4*)(vb + u*8) = o;
        }
        return;
    }

    #pragma unroll
    for (int j = 0; j < 4; ++j) {
        int cc = n0 + wx*64 + j*16 + l15;
        float bv = (zs == 0) ? bias[cc] : 0.f;
        #pragma unroll
        for (int i = 0; i < MI; ++i) {
            #pragma unroll
            for (int r = 0; r < 4; ++r) {
                int rr = m0 + wy*(MT/2) + i*16 + quad*4 + r;
                float v = acc[i][j][r] + bv;
                if (gelu) {
                    // tanh-form GELU via exp2+rcp (~7 VALU ops vs ~35 for erff;
                    // |err| <= ~3e-4 on gelu output, far below bf16 rounding)
                    float u2 = v * (0.7978845608f + 0.0356774081f * v * v);
                    float e  = __builtin_amdgcn_exp2f(u2 * 2.885390082f);  // exp(2u)
                    v = v * (1.f - __builtin_amdgcn_rcpf(e + 1.f));        // v*sigmoid(2u)
                }
                C[(size_t)rr * ldc + cc] = f2b(v);
            }
        }
    }
}

// ================= S^T-layout MFMA flash attention, 64-row K-tiles =================
#define SM_C 0.18033688011112042f   // (1/8) * log2(e)

__device__ __forceinline__ unsigned pack2bf(float a, float b)
{
    union { __bf16 h[2]; unsigned u; } t;
    t.h[0] = (__bf16)a; t.h[1] = (__bf16)b;
    return t.u;
}

// P^T (two 16-row frags) -> PV B-frag. All shuffles at full wave exec,
// per-lane cndmask after (verified in rounds 4-10).
__device__ __forceinline__ bf16x8 ptrans(const float* p0, const float* p1, int lane)
{
    int l15 = lane & 15, quad = lane >> 4;
    unsigned pk0a = pack2bf(p0[0], p0[1]), pk0b = pack2bf(p0[2], p0[3]);
    unsigned pk1a = pack2bf(p1[0], p1[1]), pk1b = pack2bf(p1[2], p1[3]);
    int sA = l15 + (quad & 1) * 32;
    int sB = sA + 16;
    int hi = quad >> 1;
    unsigned a0A = (unsigned)__shfl((int)pk0a, sA);
    unsigned a1A = (unsigned)__shfl((int)pk1a, sA);
    unsigned b0A = (unsigned)__shfl((int)pk0b, sA);
    unsigned b1A = (unsigned)__shfl((int)pk1b, sA);
    unsigned a0B = (unsigned)__shfl((int)pk0a, sB);
    unsigned a1B = (unsigned)__shfl((int)pk1a, sB);
    unsigned b0B = (unsigned)__shfl((int)pk0b, sB);
    unsigned b1B = (unsigned)__shfl((int)pk1b, sB);
    union { unsigned u[4]; bf16x8 v; } pb;
    pb.u[0] = hi ? a1A : a0A;
    pb.u[1] = hi ? b1A : b0A;
    pb.u[2] = hi ? a1B : a0B;
    pb.u[3] = hi ? b1B : b0B;
    return pb.v;
}

// grid: 768 blocks (region-interleaved qt, LONGEST FIRST), 256 threads.
// qkc: [row][1024] = q|k; ctx overwrites the q-section (disjoint ownership).
// LDS (32 KB): K tile [64 s][64 d] x2 bufs, V^T tile [64 d][64 s] x2,
// chunk-swizzled phys = c ^ (row & 7). nkt = qt+1, uniform across waves.
// Softmax uses a TILE-WIDE max (wave-uniform sm_m) => sm_l is kept as a
// per-lane partial and reduced once in the epilogue; the per-tile max
// reduce happens only inside the (rare) rescale branch.
__global__ __launch_bounds__(256, 3) void attn_kernel(
    __bf16* qkc, const __bf16* __restrict__ VT)
{
    __shared__ __align__(16) char smem[32768];

    int x = blockIdx.x;
    int region = x >> 8;          // 0,1,2
    int j = x & 255;
    int i = j >> 5;               // 0..7
    int hb = j & 31;
    // longest blocks dispatched first to shrink the tail
    int qt = (region == 0) ? (23 - i) : (region == 1) ? (8 + i) : i;
    int h = hb >> 2, b = hb & 3;

    int tid = threadIdx.x;
    int w = tid >> 6, lane = tid & 63;
    int l15 = lane & 15, quad = lane >> 4;
    int qrow0 = qt * 64 + w * 16;

    const __bf16* qp = qkc + (size_t)(b*SS + qrow0 + l15) * 1024 + h*64 + quad*8;
    bf16x8 qf0 = *(const bf16x8*)qp;
    bf16x8 qf1 = *(const bf16x8*)(qp + 32);

    // staging bases
    const __bf16* kgbase = qkc + (size_t)(b*SS) * 1024 + 512 + h*64;     // + srow*1024
    const __bf16* vgbase = VT + (size_t)(b*NH + h) * 64 * SS;            // + drow*SS
    int srow8 = lane >> 3;                        // 0..7
    int clog  = (lane & 7) ^ ((lane >> 3) & 7);   // logical chunk for DMA lane
    int sw0 = ((0*4 + quad) ^ (l15 & 7)) * 8;
    int sw1 = ((1*4 + quad) ^ (l15 & 7)) * 8;

    f32x4 o0 = {0.f,0.f,0.f,0.f}, o1 = o0, o2 = o0, o3 = o0;
    float sm_m = -1e30f, sm_l = 0.f;   // sm_l: PER-LANE partial (reduced at end)

    int nkt = qt + 1;

    #pragma unroll
    for (int q = 0; q < 2; ++q) {
        int r0 = (w*2 + q) * 8;
        gll16(kgbase + (size_t)(r0 + srow8) * 1024 + clog*8, (__bf16*)smem + r0*64);
        gll16(vgbase + (size_t)(r0 + srow8) * SS   + clog*8, (__bf16*)(smem + 16384) + r0*64);
    }
    __syncthreads();

    for (int jt = 0; jt < nkt; ++jt) {
        int buf = jt & 1;
        const __bf16* Kb = (const __bf16*)(smem + buf * 8192);
        const __bf16* Vb = (const __bf16*)(smem + 16384 + buf * 8192);
        if (jt + 1 < nkt) {
            int kb2 = (jt + 1) * 64;
            __bf16* Kn = (__bf16*)(smem + (buf ^ 1) * 8192);
            __bf16* Vn = (__bf16*)(smem + 16384 + (buf ^ 1) * 8192);
            #pragma unroll
            for (int q = 0; q < 2; ++q) {
                int r0 = (w*2 + q) * 8;
                gll16(kgbase + (size_t)(kb2 + r0 + srow8) * 1024 + clog*8, Kn + r0*64);
                gll16(vgbase + (size_t)(r0 + srow8) * SS + kb2 + clog*8,   Vn + r0*64);
            }
        }
        int kb = jt * 64;

        f32x4 s[4];
        #pragma unroll
        for (int f = 0; f < 4; ++f) {
            bf16x8 k0 = *(const bf16x8*)(Kb + (16*f + l15)*64 + sw0);
            bf16x8 k1 = *(const bf16x8*)(Kb + (16*f + l15)*64 + sw1);
            f32x4 sf = {0.f,0.f,0.f,0.f};
            sf = __builtin_amdgcn_mfma_f32_16x16x32_bf16(k0, qf0, sf, 0, 0, 0);
            sf = __builtin_amdgcn_mfma_f32_16x16x32_bf16(k1, qf1, sf, 0, 0, 0);
            s[f] = sf;
        }

        if (kb + 63 > qrow0) {
            int qrow = qrow0 + l15;
            #pragma unroll
            for (int f = 0; f < 4; ++f)
                #pragma unroll
                for (int r = 0; r < 4; ++r)
                    if (kb + 16*f + quad*4 + r > qrow) s[f][r] = -1e30f;
        }

        // per-lane tree max (no cross-lane traffic on the common path)
        float tf[4];
        #pragma unroll
        for (int f = 0; f < 4; ++f)
            tf[f] = fmaxf(fmaxf(s[f][0], s[f][1]), fmaxf(s[f][2], s[f][3]));
        float tm_lane = fmaxf(fmaxf(tf[0], tf[1]), fmaxf(tf[2], tf[3]));

        // defer-max (T13): rescale only if some lane's max grows past
        // sm_m + 64 raw-score units (=> P <= e^8, safe in fp32/bf16).
        if (!__all(tm_lane <= sm_m + 64.f)) {
            float tm = tm_lane;
            tm = fmaxf(tm, __shfl_xor(tm, 16));
            tm = fmaxf(tm, __shfl_xor(tm, 32));
            float mnew = fmaxf(sm_m, tm);
            float alpha = __builtin_amdgcn_exp2f((sm_m - mnew) * SM_C);  // uniform
            sm_l *= alpha;
            o0 *= alpha; o1 *= alpha; o2 *= alpha; o3 *= alpha;
            sm_m = mnew;
        }

        // p = exp2(s*C - m*C): one fma + one exp2 per element
        float negmC = -sm_m * SM_C;
        float pp[4][4];
        float rf[4];
        #pragma unroll
        for (int f = 0; f < 4; ++f) {
            #pragma unroll
            for (int r = 0; r < 4; ++r)
                pp[f][r] = __builtin_amdgcn_exp2f(fmaf(s[f][r], SM_C, negmC));
            rf[f] = (pp[f][0] + pp[f][1]) + (pp[f][2] + pp[f][3]);
        }
        sm_l += (rf[0] + rf[1]) + (rf[2] + rf[3]);   // per-lane partial only

        bf16x8 pb01 = ptrans(pp[0], pp[1], lane);
        bf16x8 pb23 = ptrans(pp[2], pp[3], lane);

        #pragma unroll
        for (int ii = 0; ii < 4; ++ii) {
            bf16x8 va = *(const bf16x8*)(Vb + (16*ii + l15)*64 + sw0);
            bf16x8 vb = *(const bf16x8*)(Vb + (16*ii + l15)*64 + sw1);
            f32x4* op = (ii == 0) ? &o0 : (ii == 1) ? &o1 : (ii == 2) ? &o2 : &o3;
            *op = __builtin_amdgcn_mfma_f32_16x16x32_bf16(va, pb01, *op, 0, 0, 0);
            *op = __builtin_amdgcn_mfma_f32_16x16x32_bf16(vb, pb23, *op, 0, 0, 0);
        }
        __syncthreads();
    }

    // epilogue: reduce the deferred row-sum (lanes sharing l15), then
    // O^T regs -> LDS -> coalesced bf16 stores
    sm_l += __shfl_xor(sm_l, 16);
    sm_l += __shfl_xor(sm_l, 32);
    float* otw = (float*)smem + w * 16 * 68;
    float inv = 1.f / sm_l;
    #pragma unroll
    for (int r = 0; r < 4; ++r) {
        otw[l15*68 +  0 + quad*4 + r] = o0[r] * inv;
        otw[l15*68 + 16 + quad*4 + r] = o1[r] * inv;
        otw[l15*68 + 32 + quad*4 + r] = o2[r] * inv;
        otw[l15*68 + 48 + quad*4 + r] = o3[r] * inv;
    }
    asm volatile("s_waitcnt lgkmcnt(0)" ::: "memory");
    int row = lane >> 2, ch = (lane & 3) * 16;
    union { __bf16 hh[16]; uint4 q4[2]; } ob;
    #pragma unroll
    for (int t2 = 0; t2 < 16; ++t2) ob.hh[t2] = f2b(otw[row*68 + ch + t2]);
    __bf16* cp = qkc + (size_t)(b*SS + qrow0 + row) * 1024 + h*64 + ch;
    *(uint4*)cp = ob.q4[0];
    *(uint4*)(cp + 8) = ob.q4[1];
}

// ================= final projection (bf16 h) =================
__global__ __launch_bounds__(256) void proj_kernel(
    const __bf16* __restrict__ h_bf, const float* __restrict__ Wp,
    const float* __restrict__ bp, float* __restrict__ out)
{
    int rid = blockIdx.x * 8 + (threadIdx.x >> 5);
    int col = threadIdx.x & 31;
    int b = rid / TT, i = rid - b * TT;
    const __bf16* x = h_bf + ((size_t)(b*SS) + 3*i + 1) * HDIM;
    float acc = bp[col];
    for (int k8 = 0; k8 < HDIM/8; ++k8) {
        bf16x8 x8 = *(const bf16x8*)(x + k8*8);
        #pragma unroll
        for (int u = 0; u < 8; ++u)
            acc += (float)x8[u] * Wp[(k8*8 + u) * ADIM + col];
    }
    out[(size_t)rid * ADIM + col] = acc;
}

extern "C" void kernel_launch(void* const* d_in, const int* in_sizes, int n_in,
                              void* d_out, int out_size, void* d_ws, size_t ws_size,
                              hipStream_t stream)
{
    (void)in_sizes; (void)n_in; (void)out_size; (void)ws_size;
    const int*   timesteps = (const int*)  d_in[0];
    const float* state0    = (const float*)d_in[1];
    const float* state1    = (const float*)d_in[2];
    const float* actions   = (const float*)d_in[3];
    const float* time_emb  = (const float*)d_in[4];
    const float* Ws  = (const float*)d_in[5];
    const float* bs  = (const float*)d_in[6];
    const float* Wa  = (const float*)d_in[7];
    const float* ba  = (const float*)d_in[8];
    const float* Wq  = (const float*)d_in[9];
    const float* bq  = (const float*)d_in[10];
    const float* Wk  = (const float*)d_in[11];
    const float* bk  = (const float*)d_in[12];
    const float* Wv  = (const float*)d_in[13];
    const float* bv  = (const float*)d_in[14];
    const float* Wo  = (const float*)d_in[15];
    const float* bo  = (const float*)d_in[16];
    const float* W1  = (const float*)d_in[17];
    const float* b1  = (const float*)d_in[18];
    const float* W2  = (const float*)d_in[19];
    const float* b2  = (const float*)d_in[20];
    const float* ln1g = (const float*)d_in[21];
    const float* ln1b = (const float*)d_in[22];
    const float* ln2g = (const float*)d_in[23];
    const float* ln2b = (const float*)d_in[24];
    const float* elng = (const float*)d_in[25];
    const float* elnb = (const float*)d_in[26];
    const float* Wp   = (const float*)d_in[27];
    const float* bp   = (const float*)d_in[28];
    float* out = (float*)d_out;

    char* p = (char*)d_ws;
    __bf16* h_bf = (__bf16*)p;           p += SZE * 2;                  // residual (bf16)
    __bf16* qk   = (__bf16*)p;           p += (size_t)MS * 1024 * 2;   // q|k; q-sec doubles as ctx
    __bf16* VT   = (__bf16*)p;           p += SZE * 2;
    /* hid extension */                  p += SZE * 2;                  // hid = qk..VT..ext (MSx2048)
    __bf16* tmp  = (__bf16*)p;           p += SZE * 2 * 2;              // split-K partials 0..1
    __bf16* wqkvT = (__bf16*)p;          p += (size_t)NBLK * 1536 * 512 * 2;
    __bf16* woT   = (__bf16*)p;          p += (size_t)NBLK * 512 * 512 * 2;
    __bf16* w1T   = (__bf16*)p;          p += (size_t)NBLK * 2048 * 512 * 2;
    __bf16* w2T   = (__bf16*)p;          p += (size_t)NBLK * 512 * 2048 * 2;
    float*  biasq = (float*)p;           p += (size_t)NBLK * 1536 * 4;
    __bf16* hid   = qk;                  // MS x 2048 bf16 spans qk+VT+ext

    embed_ln_kernel<<<dim3(TT/8, 3, BB), 512, 0, stream>>>(timesteps, state0, state1, actions,
                                                           time_emb, Ws, bs, Wa, ba, elng, elnb, h_bf);

    // pack all 6 layers in one launch
    pack_kernel<<<dim3(769, NBLK), 256, 0, stream>>>(Wq, Wk, Wv, Wo, W1, W2, bq, bk, bv,
                                                     wqkvT, woT, w1T, w2T, biasq);

    dim3 gQKV(1536/128, MS/64, 1);     // 12 x 96  (MT=64, 4.5 blocks/CU)
    dim3 gO  (512/128,  MS/64, 2);     // 4 x 96 x 2  (split-K=2, MT=64)
    dim3 gF1 (2048/128, MS/64, 1);     // 16 x 96  (MT=64, 6 blocks/CU)

    for (int lyr = 0; lyr < NBLK; ++lyr) {
        const __bf16* wqkvT_l = wqkvT + (size_t)lyr * 1536 * 512;
        const __bf16* woT_l   = woT   + (size_t)lyr * 512 * 512;
        const __bf16* w1T_l   = w1T   + (size_t)lyr * 2048 * 512;
        const __bf16* w2T_l   = w2T   + (size_t)lyr * 512 * 2048;
        const float*  biasq_l = biasq + (size_t)lyr * 1536;

        // QKV: q|k rows -> qk (ldc 1024); V tiles transposed -> VT in-epilogue
        gemm_mfma<64, true><<<gQKV, 256, 0, stream>>>(h_bf, wqkvT_l, biasq_l, qk, VT,
                                                      1536, 512, 512, 512, 1024, 0, 0);
        attn_kernel<<<dim3(768), 256, 0, stream>>>(qk, VT);
        // WO: A = ctx (q-section, lda 1024); split-K=2 (256 each)
        gemm_mfma<64, false><<<gO, 256, 0, stream>>>(qk, woT_l, bo + lyr*HDIM, tmp, nullptr,
                                                     512, 256, 1024, 512, 512, 0, SZE);
        ln_add_kernel<2><<<MS/4, 256, 0, stream>>>(h_bf, tmp,
                                                   ln1g + lyr*HDIM, ln1b + lyr*HDIM);
        gemm_mfma<64, false><<<gF1, 256, 0, stream>>>(h_bf, w1T_l, b1 + lyr*DFF, hid, nullptr,
                                                      2048, 512, 512, 512, 2048, 1, 0);
        // W2: split-K=2 (1024 each), MT=64
        gemm_mfma<64, false><<<gO, 256, 0, stream>>>(hid, w2T_l, b2 + lyr*HDIM, tmp, nullptr,
                                                     512, 1024, 2048, 2048, 512, 0, SZE);
        ln_add_kernel<2><<<MS/4, 256, 0, stream>>>(h_bf, tmp,
                                                   ln2g + lyr*HDIM, ln2b + lyr*HDIM);
    }

    proj_kernel<<<(BB*TT)/8, 256, 0, stream>>>(h_bf, Wp, bp, out);
}

// Round 8
// 908.234 us; speedup vs baseline: 1.1118x; 1.0139x over previous
//
#include <hip/hip_runtime.h>
#include <hip/hip_bf16.h>
#include <math.h>

#define BB 4
#define TT 512
#define SDIM 64
#define ADIM 32
#define HDIM 512
#define NH 8
#define NBLK 6
#define DFF 2048
#define SS 1536          // 3*T
#define DH 64
#define MS (BB*SS)       // 6144 rows
#define SZE ((size_t)MS * HDIM)   // elements in one [MS][HDIM] partial

typedef __attribute__((ext_vector_type(8))) __bf16 bf16x8;
typedef __attribute__((ext_vector_type(4))) float f32x4;

__device__ __forceinline__ __bf16 f2b(float x) { return (__bf16)x; }

// async global->LDS, 16 B per lane; LDS dest = wave-uniform base + lane*16
__device__ __forceinline__ void gll16(const void* g, void* l) {
    __builtin_amdgcn_global_load_lds(
        (const __attribute__((address_space(1))) unsigned int*)g,
        (__attribute__((address_space(3))) unsigned int*)l, 16, 0, 0);
}

// ================= embed + LN -> h_bf (bf16 residual stream) =================
// 8 rows of the SAME type per block: W read once from L2 per 8 rows.
// grid (64, 3, 4): chunk, type t, batch b. 512 threads.
__global__ __launch_bounds__(512) void embed_ln_kernel(
    const int* __restrict__ timesteps,
    const float* __restrict__ state0, const float* __restrict__ state1,
    const float* __restrict__ actions, const float* __restrict__ time_emb,
    const float* __restrict__ Ws, const float* __restrict__ bs,
    const float* __restrict__ Wa, const float* __restrict__ ba,
    const float* __restrict__ eg, const float* __restrict__ eb,
    __bf16* __restrict__ h_bf)
{
    __shared__ float xs[8][64];
    __shared__ float acc_s[8][512];
    __shared__ int tss[8];
    int c = blockIdx.x, t = blockIdx.y, b = blockIdx.z;
    int i0 = c * 8;
    int tid = threadIdx.x;
    int K = (t == 2) ? ADIM : SDIM;
    int ksh = (t == 2) ? 5 : 6;
    const float* W    = (t == 2) ? Wa : Ws;
    const float* bias = (t == 2) ? ba : bs;
    const float* src  = (t == 0) ? state0  + ((size_t)(b*TT + i0)) * SDIM
                      : (t == 1) ? state1  + ((size_t)(b*TT + i0)) * SDIM
                                 : actions + ((size_t)(b*TT + i0)) * ADIM;

    if (tid < 8) tss[tid] = timesteps[b*TT + i0 + tid];
    for (int idx = tid; idx < 8 * K; idx += 512) {
        int r = idx >> ksh, kk = idx & (K - 1);
        xs[r][kk] = src[r * K + kk];           // row stride == K, contiguous
    }
    __syncthreads();

    float acc[8];
    #pragma unroll
    for (int r = 0; r < 8; ++r)
        acc[r] = bias[tid] + time_emb[(size_t)tss[r] * HDIM + tid];
    for (int kk = 0; kk < K; ++kk) {
        float w = W[(size_t)kk * HDIM + tid];
        #pragma unroll
        for (int r = 0; r < 8; ++r) acc[r] += xs[r][kk] * w;
    }
    #pragma unroll
    for (int r = 0; r < 8; ++r) acc_s[r][tid] = acc[r];
    __syncthreads();

    // wave w owns row w: vector read, shuffle-only LN, 16B store
    int w = tid >> 6, lane = tid & 63;
    float4 p0 = *(const float4*)&acc_s[w][lane * 8];
    float4 p1 = *(const float4*)&acc_s[w][lane * 8 + 4];
    float v[8] = {p0.x, p0.y, p0.z, p0.w, p1.x, p1.y, p1.z, p1.w};
    float s = 0.f, sq = 0.f;
    #pragma unroll
    for (int u = 0; u < 8; ++u) { s += v[u]; sq += v[u] * v[u]; }
    #pragma unroll
    for (int off = 1; off < 64; off <<= 1) { s += __shfl_xor(s, off); sq += __shfl_xor(sq, off); }
    float mean = s * (1.f / HDIM);
    float var  = sq * (1.f / HDIM) - mean * mean;
    float inv  = rsqrtf(var + 1e-5f);
    float4 g0 = *(const float4*)(eg + lane * 8), g1 = *(const float4*)(eg + lane * 8 + 4);
    float4 b0 = *(const float4*)(eb + lane * 8), b1 = *(const float4*)(eb + lane * 8 + 4);
    float gg[8] = {g0.x, g0.y, g0.z, g0.w, g1.x, g1.y, g1.z, g1.w};
    float bbv[8] = {b0.x, b0.y, b0.z, b0.w, b1.x, b1.y, b1.z, b1.w};
    __bf16 o8[8];
    #pragma unroll
    for (int u = 0; u < 8; ++u) o8[u] = f2b((v[u] - mean) * inv * gg[u] + bbv[u]);
    int row = b * SS + (i0 + w) * 3 + t;
    *(uint4*)(h_bf + (size_t)row * HDIM + lane * 8) = *(uint4*)o8;
}

// ================= residual add (NP bf16 partials, SZE-strided) + LN =================
// wave-per-row: bf16x8 loads, shuffle-only reduction, no barriers.
// grid MS/4 = 1536 blocks x 256 threads.
template<int NP>
__global__ __launch_bounds__(256) void ln_add_kernel(
    __bf16* __restrict__ h_bf, const __bf16* __restrict__ parts,
    const float* __restrict__ g, const float* __restrict__ bvec)
{
    int w = threadIdx.x >> 6, lane = threadIdx.x & 63;
    int row = blockIdx.x * 4 + w;
    size_t base = (size_t)row * HDIM + lane * 8;
    bf16x8 h8 = *(const bf16x8*)(h_bf + base);
    bf16x8 p8[NP];
    #pragma unroll
    for (int p = 0; p < NP; ++p) p8[p] = *(const bf16x8*)(parts + p * SZE + base);
    float v[8], s = 0.f, sq = 0.f;
    #pragma unroll
    for (int u = 0; u < 8; ++u) {
        float acc = (float)h8[u];
        #pragma unroll
        for (int p = 0; p < NP; ++p) acc += (float)p8[p][u];
        v[u] = acc;
        s += acc; sq += acc * acc;
    }
    #pragma unroll
    for (int off = 1; off < 64; off <<= 1) { s += __shfl_xor(s, off); sq += __shfl_xor(sq, off); }
    float mean = s * (1.f / HDIM);
    float var  = sq * (1.f / HDIM) - mean * mean;
    float inv  = rsqrtf(var + 1e-5f);
    float4 g0 = *(const float4*)(g + lane * 8), g1 = *(const float4*)(g + lane * 8 + 4);
    float4 b0 = *(const float4*)(bvec + lane * 8), b1 = *(const float4*)(bvec + lane * 8 + 4);
    float gg[8] = {g0.x, g0.y, g0.z, g0.w, g1.x, g1.y, g1.z, g1.w};
    float bbv[8] = {b0.x, b0.y, b0.z, b0.w, b1.x, b1.y, b1.z, b1.w};
    __bf16 o8[8];
    #pragma unroll
    for (int u = 0; u < 8; ++u) o8[u] = f2b((v[u] - mean) * inv * gg[u] + bbv[u]);
    *(uint4*)(h_bf + base) = *(uint4*)o8;
}

// ================= weight pack: fp32 [K][N] -> bf16 [N][K], all 6 layers =================
// grid (769, 6): blockIdx.y = layer.
__global__ __launch_bounds__(256) void pack_kernel(
    const float* __restrict__ Wq, const float* __restrict__ Wk,
    const float* __restrict__ Wv, const float* __restrict__ Wo,
    const float* __restrict__ W1, const float* __restrict__ W2,
    const float* __restrict__ bq_, const float* __restrict__ bk_, const float* __restrict__ bv_,
    __bf16* __restrict__ wqkvT, __bf16* __restrict__ woT,
    __bf16* __restrict__ w1T, __bf16* __restrict__ w2T, float* __restrict__ biasq)
{
    int lyr = blockIdx.y;
    const float* wq = Wq + (size_t)lyr * HDIM * HDIM;
    const float* wk = Wk + (size_t)lyr * HDIM * HDIM;
    const float* wv = Wv + (size_t)lyr * HDIM * HDIM;
    const float* wo = Wo + (size_t)lyr * HDIM * HDIM;
    const float* w1 = W1 + (size_t)lyr * HDIM * DFF;
    const float* w2 = W2 + (size_t)lyr * DFF * HDIM;
    const float* bqL = bq_ + (size_t)lyr * HDIM;
    const float* bkL = bk_ + (size_t)lyr * HDIM;
    const float* bvL = bv_ + (size_t)lyr * HDIM;
    wqkvT += (size_t)lyr * 1536 * 512;
    woT   += (size_t)lyr * 512 * 512;
    w1T   += (size_t)lyr * 2048 * 512;
    w2T   += (size_t)lyr * 512 * 2048;
    biasq += (size_t)lyr * 1536;

    int bid = blockIdx.x;
    int tid = threadIdx.x;
    if (bid == 768) {
        for (int i = tid; i < 1536; i += 256)
            biasq[i] = (i < 512) ? bqL[i] : ((i < 1024) ? bkL[i-512] : bvL[i-1024]);
        return;
    }
    __shared__ float Ls[64][65];
    const float* src; __bf16* dst; int K, N, kt, nt;
    if (bid < 192) {
        int sec = bid / 64, t = bid % 64;
        src = (sec == 0) ? wq : (sec == 1) ? wk : wv;
        dst = wqkvT + (size_t)sec * 512 * 512;
        K = 512; N = 512; nt = t >> 3; kt = t & 7;
    } else if (bid < 256) {
        int t = bid - 192; src = wo; dst = woT; K = 512; N = 512; nt = t >> 3; kt = t & 7;
    } else if (bid < 512) {
        int t = bid - 256; src = w1; dst = w1T; K = 512; N = 2048; nt = t >> 3; kt = t & 7;
    } else {
        int t = bid - 512; src = w2; dst = w2T; K = 2048; N = 512; nt = t & 7; kt = t >> 3;
    }
    int k0 = kt * 64, n0 = nt * 64;
    int rr = tid >> 4, cc = (tid & 15) * 4;
    #pragma unroll
    for (int p = 0; p < 4; ++p) {
        float4 v = *(const float4*)(src + (size_t)(k0 + rr + p*16) * N + n0 + cc);
        Ls[rr + p*16][cc] = v.x; Ls[rr + p*16][cc+1] = v.y;
        Ls[rr + p*16][cc+2] = v.z; Ls[rr + p*16][cc+3] = v.w;
    }
    __syncthreads();
    int nn = tid >> 3, kc = (tid & 7) * 8;
    #pragma unroll
    for (int p = 0; p < 2; ++p) {
        __bf16 t8[8];
        #pragma unroll
        for (int t2 = 0; t2 < 8; ++t2) t8[t2] = f2b(Ls[kc + t2][nn + p*32]);
        *(uint4*)(dst + (size_t)(n0 + nn + p*32) * K + k0 + kc) = *(uint4*)t8;
    }
}

// ================= bf16 MFMA GEMM, double-buffered async LDS staging =================
// Round-7 proven structure: 2 buffers, one __syncthreads per K-step,
// prefetch kt+1 inside the loop, direct C-write.
// BK = K-tile width (32 or 64). BK=64 halves the barrier count at the same
// 3-blocks/CU residency (use only where grid <= 768).
// A: bf16 [M][lda].  Bt: bf16 [N][ldb].  C: bf16 [M][ldc].
// Split-K via blockIdx.z; bias applied only on z==0.
// VTMODE: blocks with n0 >= 1024 write their tile TRANSPOSED to VTout.
template<int MT, int BK, bool VTMODE>
__global__ __launch_bounds__(256) void gemm_mfma(
    const __bf16* __restrict__ A, const __bf16* __restrict__ Bt,
    const float* __restrict__ bias, __bf16* __restrict__ C,
    __bf16* __restrict__ VTout,
    int N, int Ksub, int lda, int ldb, int ldc, int gelu, size_t cSplitStride)
{
    constexpr int MI = MT / 32;
    constexpr int KC = BK / 32;                  // 32-wide k-chunks per step
    constexpr int CH = BK / 8;                   // 8-elem chunks per row
    constexpr int RPC = 64 / CH;                 // rows per wave-call
    constexpr int SMB = 2*MT*BK*2 + 2*128*BK*2;
    __shared__ __align__(16) char sm[SMB];
    __bf16* As = (__bf16*)sm;                    // [2][MT][BK]
    __bf16* Bs = (__bf16*)(sm + 2*MT*BK*2);      // [2][128][BK]
    int tid = threadIdx.x;
    int wave = tid >> 6, lane = tid & 63;
    int l15 = lane & 15, quad = lane >> 4;
    int wy = wave >> 1, wx = wave & 1;
    int m0 = blockIdx.y * MT, n0 = blockIdx.x * 128;
    int zs = blockIdx.z;
    int kbase = zs * Ksub;
    C += (size_t)zs * cSplitStride;

    int srow, clog;
    if (BK == 32) { srow = lane >> 2; clog = (lane & 3) ^ ((lane >> 3) & 3); }
    else          { srow = lane >> 3; clog = (lane & 7) ^ ((lane >> 3) & 7); }

    f32x4 acc[MI][4];
    #pragma unroll
    for (int i = 0; i < MI; ++i)
        #pragma unroll
        for (int j = 0; j < 4; ++j) acc[i][j] = (f32x4){0.f,0.f,0.f,0.f};

    const __bf16* Abase = A  + (size_t)m0 * lda + kbase + clog * 8;
    const __bf16* Bbase = Bt + (size_t)n0 * ldb + kbase + clog * 8;
    int NK = Ksub / BK;

    constexpr int ACALLS = MT / (4 * RPC);       // per wave
    constexpr int BCALLS = 128 / (4 * RPC);

    // prologue: stage k-tile 0 into buffer 0
    #pragma unroll
    for (int q = 0; q < ACALLS; ++q) {
        int r0 = (wave * ACALLS + q) * RPC;
        gll16(Abase + (size_t)(r0 + srow) * lda, As + r0*BK);
    }
    #pragma unroll
    for (int q = 0; q < BCALLS; ++q) {
        int r0 = (wave * BCALLS + q) * RPC;
        gll16(Bbase + (size_t)(r0 + srow) * ldb, Bs + r0*BK);
    }

    for (int kt = 0; kt < NK; ++kt) {
        int buf = kt & 1;
        __syncthreads();   // drains the loads for `buf` (issued one full iter ago)
        if (kt + 1 < NK) {
            int k0 = (kt + 1) * BK;
            #pragma unroll
            for (int q = 0; q < ACALLS; ++q) {
                int r0 = (wave * ACALLS + q) * RPC;
                gll16(Abase + (size_t)(r0 + srow) * lda + k0, As + ((buf^1)*MT + r0)*BK);
            }
            #pragma unroll
            for (int q = 0; q < BCALLS; ++q) {
                int r0 = (wave * BCALLS + q) * RPC;
                gll16(Bbase + (size_t)(r0 + srow) * ldb + k0, Bs + ((buf^1)*128 + r0)*BK);
            }
        }
        bf16x8 af[KC][MI], bf[KC][4];
        #pragma unroll
        for (int kk = 0; kk < KC; ++kk) {
            int pch;
            if (BK == 32) pch = (quad ^ ((l15 >> 1) & 3)) * 8;
            else          pch = ((kk*4 + quad) ^ (l15 & 7)) * 8;
            #pragma unroll
            for (int i = 0; i < MI; ++i)
                af[kk][i] = *(const bf16x8*)&As[(buf*MT + wy*(MT/2) + i*16 + l15)*BK + pch];
            #pragma unroll
            for (int j = 0; j < 4; ++j)
                bf[kk][j] = *(const bf16x8*)&Bs[(buf*128 + wx*64 + j*16 + l15)*BK + pch];
        }
        #pragma unroll
        for (int kk = 0; kk < KC; ++kk)
            #pragma unroll
            for (int i = 0; i < MI; ++i)
                #pragma unroll
                for (int j = 0; j < 4; ++j)
                    acc[i][j] = __builtin_amdgcn_mfma_f32_16x16x32_bf16(af[kk][i], bf[kk][j], acc[i][j], 0, 0, 0);
    }

    if (VTMODE && n0 >= 1024) {
        // transpose tile (MT s x 128 d) into VT via LDS (reuse staging)
        constexpr int SCH = MT / 4;       // s-chunks of 4
        __syncthreads();
        __bf16* T = (__bf16*)sm;          // logical [128 d][MT s], s-chunk swizzled
        #pragma unroll
        for (int j = 0; j < 4; ++j) {
            int dl = wx*64 + j*16 + l15;
            float bv = bias[n0 + dl];
            int xm = dl & (SCH - 1);
            #pragma unroll
            for (int i = 0; i < MI; ++i) {
                int sc = wy*(MI*4) + i*4 + quad;      // 4-elem s-chunk index
                int phys = sc ^ xm;
                __bf16 v4[4];
                #pragma unroll
                for (int r = 0; r < 4; ++r) v4[r] = f2b(acc[i][j][r] + bv);
                *(uint2*)(T + dl*MT + phys*4) = *(uint2*)v4;
            }
        }
        __syncthreads();
        constexpr int SPT = MT / 2;       // s per thread (2 threads per d row)
        int dl = tid >> 1, sh = (tid & 1) * SPT;
        int dglob = n0 - 1024 + dl;
        int bb = m0 / SS, srel = m0 - bb*SS;
        __bf16* vb = VTout + ((size_t)(bb*NH + (dglob >> 6)) * 64 + (dglob & 63)) * SS + srel + sh;
        int xm = dl & (SCH - 1);
        #pragma unroll
        for (int u = 0; u < SPT/8; ++u) {
            int c0 = (sh >> 2) + u*2;
            uint2 lo = *(const uint2*)(T + dl*MT + ((c0    ) ^ xm)*4);
            uint2 hi = *(const uint2*)(T + dl*MT + ((c0 + 1) ^ xm)*4);
            uint4 o; o.x = lo.x; o.y = lo.y; o.z = hi.x; o.w = hi.y;
            *(uint4*)(vb + u*8) = o;
        }
        return;
    }

    #pragma unroll
    for (int j = 0; j < 4; ++j) {
        int cc = n0 + wx*64 + j*16 + l15;
        float bv = (zs == 0) ? bias[cc] : 0.f;
        #pragma unroll
        for (int i = 0; i < MI; ++i) {
            #pragma unroll
            for (int r = 0; r < 4; ++r) {
                int rr = m0 + wy*(MT/2) + i*16 + quad*4 + r;
                float v = acc[i][j][r] + bv;
                if (gelu) {
                    // tanh-form GELU via exp2+rcp (~7 VALU ops vs ~35 for erff;
                    // |err| <= ~3e-4 on gelu output, far below bf16 rounding)
                    float u2 = v * (0.7978845608f + 0.0356774081f * v * v);
                    float e  = __builtin_amdgcn_exp2f(u2 * 2.885390082f);  // exp(2u)
                    v = v * (1.f - __builtin_amdgcn_rcpf(e + 1.f));        // v*sigmoid(2u)
                }
                C[(size_t)rr * ldc + cc] = f2b(v);
            }
        }
    }
}

// ================= S^T-layout MFMA flash attention, 64-row K-tiles =================
#define SM_C 0.18033688011112042f   // (1/8) * log2(e)

__device__ __forceinline__ unsigned pack2bf(float a, float b)
{
    union { __bf16 h[2]; unsigned u; } t;
    t.h[0] = (__bf16)a; t.h[1] = (__bf16)b;
    return t.u;
}

// P^T (two 16-row frags) -> PV B-frag. All shuffles at full wave exec,
// per-lane cndmask after (verified in rounds 4-10).
__device__ __forceinline__ bf16x8 ptrans(const float* p0, const float* p1, int lane)
{
    int l15 = lane & 15, quad = lane >> 4;
    unsigned pk0a = pack2bf(p0[0], p0[1]), pk0b = pack2bf(p0[2], p0[3]);
    unsigned pk1a = pack2bf(p1[0], p1[1]), pk1b = pack2bf(p1[2], p1[3]);
    int sA = l15 + (quad & 1) * 32;
    int sB = sA + 16;
    int hi = quad >> 1;
    unsigned a0A = (unsigned)__shfl((int)pk0a, sA);
    unsigned a1A = (unsigned)__shfl((int)pk1a, sA);
    unsigned b0A = (unsigned)__shfl((int)pk0b, sA);
    unsigned b1A = (unsigned)__shfl((int)pk1b, sA);
    unsigned a0B = (unsigned)__shfl((int)pk0a, sB);
    unsigned a1B = (unsigned)__shfl((int)pk1a, sB);
    unsigned b0B = (unsigned)__shfl((int)pk0b, sB);
    unsigned b1B = (unsigned)__shfl((int)pk1b, sB);
    union { unsigned u[4]; bf16x8 v; } pb;
    pb.u[0] = hi ? a1A : a0A;
    pb.u[1] = hi ? b1A : b0A;
    pb.u[2] = hi ? a1B : a0B;
    pb.u[3] = hi ? b1B : b0B;
    return pb.v;
}

// grid: 768 blocks (region-interleaved qt, LONGEST FIRST), 256 threads.
// qkc: [row][1024] = q|k; ctx overwrites the q-section (disjoint ownership).
// LDS (32 KB): K tile [64 s][64 d] x2 bufs, V^T tile [64 d][64 s] x2,
// chunk-swizzled phys = c ^ (row & 7). nkt = qt+1, uniform across waves.
// Softmax uses a TILE-WIDE max (wave-uniform sm_m) => sm_l is kept as a
// per-lane partial and reduced once in the epilogue; the per-tile max
// reduce happens only inside the (rare) rescale branch.
__global__ __launch_bounds__(256, 3) void attn_kernel(
    __bf16* qkc, const __bf16* __restrict__ VT)
{
    __shared__ __align__(16) char smem[32768];

    int x = blockIdx.x;
    int region = x >> 8;          // 0,1,2
    int j = x & 255;
    int i = j >> 5;               // 0..7
    int hb = j & 31;
    // longest blocks dispatched first to shrink the tail
    int qt = (region == 0) ? (23 - i) : (region == 1) ? (8 + i) : i;
    int h = hb >> 2, b = hb & 3;

    int tid = threadIdx.x;
    int w = tid >> 6, lane = tid & 63;
    int l15 = lane & 15, quad = lane >> 4;
    int qrow0 = qt * 64 + w * 16;

    const __bf16* qp = qkc + (size_t)(b*SS + qrow0 + l15) * 1024 + h*64 + quad*8;
    bf16x8 qf0 = *(const bf16x8*)qp;
    bf16x8 qf1 = *(const bf16x8*)(qp + 32);

    // staging bases
    const __bf16* kgbase = qkc + (size_t)(b*SS) * 1024 + 512 + h*64;     // + srow*1024
    const __bf16* vgbase = VT + (size_t)(b*NH + h) * 64 * SS;            // + drow*SS
    int srow8 = lane >> 3;                        // 0..7
    int clog  = (lane & 7) ^ ((lane >> 3) & 7);   // logical chunk for DMA lane
    int sw0 = ((0*4 + quad) ^ (l15 & 7)) * 8;
    int sw1 = ((1*4 + quad) ^ (l15 & 7)) * 8;

    f32x4 o0 = {0.f,0.f,0.f,0.f}, o1 = o0, o2 = o0, o3 = o0;
    float sm_m = -1e30f, sm_l = 0.f;   // sm_l: PER-LANE partial (reduced at end)

    int nkt = qt + 1;

    #pragma unroll
    for (int q = 0; q < 2; ++q) {
        int r0 = (w*2 + q) * 8;
        gll16(kgbase + (size_t)(r0 + srow8) * 1024 + clog*8, (__bf16*)smem + r0*64);
        gll16(vgbase + (size_t)(r0 + srow8) * SS   + clog*8, (__bf16*)(smem + 16384) + r0*64);
    }
    __syncthreads();

    for (int jt = 0; jt < nkt; ++jt) {
        int buf = jt & 1;
        const __bf16* Kb = (const __bf16*)(smem + buf * 8192);
        const __bf16* Vb = (const __bf16*)(smem + 16384 + buf * 8192);
        if (jt + 1 < nkt) {
            int kb2 = (jt + 1) * 64;
            __bf16* Kn = (__bf16*)(smem + (buf ^ 1) * 8192);
            __bf16* Vn = (__bf16*)(smem + 16384 + (buf ^ 1) * 8192);
            #pragma unroll
            for (int q = 0; q < 2; ++q) {
                int r0 = (w*2 + q) * 8;
                gll16(kgbase + (size_t)(kb2 + r0 + srow8) * 1024 + clog*8, Kn + r0*64);
                gll16(vgbase + (size_t)(r0 + srow8) * SS + kb2 + clog*8,   Vn + r0*64);
            }
        }
        int kb = jt * 64;

        f32x4 s[4];
        #pragma unroll
        for (int f = 0; f < 4; ++f) {
            bf16x8 k0 = *(const bf16x8*)(Kb + (16*f + l15)*64 + sw0);
            bf16x8 k1 = *(const bf16x8*)(Kb + (16*f + l15)*64 + sw1);
            f32x4 sf = {0.f,0.f,0.f,0.f};
            sf = __builtin_amdgcn_mfma_f32_16x16x32_bf16(k0, qf0, sf, 0, 0, 0);
            sf = __builtin_amdgcn_mfma_f32_16x16x32_bf16(k1, qf1, sf, 0, 0, 0);
            s[f] = sf;
        }

        if (kb + 63 > qrow0) {
            int qrow = qrow0 + l15;
            #pragma unroll
            for (int f = 0; f < 4; ++f)
                #pragma unroll
                for (int r = 0; r < 4; ++r)
                    if (kb + 16*f + quad*4 + r > qrow) s[f][r] = -1e30f;
        }

        // per-lane tree max (no cross-lane traffic on the common path)
        float tf[4];
        #pragma unroll
        for (int f = 0; f < 4; ++f)
            tf[f] = fmaxf(fmaxf(s[f][0], s[f][1]), fmaxf(s[f][2], s[f][3]));
        float tm_lane = fmaxf(fmaxf(tf[0], tf[1]), fmaxf(tf[2], tf[3]));

        // defer-max (T13): rescale only if some lane's max grows past
        // sm_m + 64 raw-score units (=> P <= e^8, safe in fp32/bf16).
        if (!__all(tm_lane <= sm_m + 64.f)) {
            float tm = tm_lane;
            tm = fmaxf(tm, __shfl_xor(tm, 16));
            tm = fmaxf(tm, __shfl_xor(tm, 32));
            float mnew = fmaxf(sm_m, tm);
            float alpha = __builtin_amdgcn_exp2f((sm_m - mnew) * SM_C);  // uniform
            sm_l *= alpha;
            o0 *= alpha; o1 *= alpha; o2 *= alpha; o3 *= alpha;
            sm_m = mnew;
        }

        // p = exp2(s*C - m*C): one fma + one exp2 per element
        float negmC = -sm_m * SM_C;
        float pp[4][4];
        float rf[4];
        #pragma unroll
        for (int f = 0; f < 4; ++f) {
            #pragma unroll
            for (int r = 0; r < 4; ++r)
                pp[f][r] = __builtin_amdgcn_exp2f(fmaf(s[f][r], SM_C, negmC));
            rf[f] = (pp[f][0] + pp[f][1]) + (pp[f][2] + pp[f][3]);
        }
        sm_l += (rf[0] + rf[1]) + (rf[2] + rf[3]);   // per-lane partial only

        bf16x8 pb01 = ptrans(pp[0], pp[1], lane);
        bf16x8 pb23 = ptrans(pp[2], pp[3], lane);

        #pragma unroll
        for (int ii = 0; ii < 4; ++ii) {
            bf16x8 va = *(const bf16x8*)(Vb + (16*ii + l15)*64 + sw0);
            bf16x8 vb = *(const bf16x8*)(Vb + (16*ii + l15)*64 + sw1);
            f32x4* op = (ii == 0) ? &o0 : (ii == 1) ? &o1 : (ii == 2) ? &o2 : &o3;
            *op = __builtin_amdgcn_mfma_f32_16x16x32_bf16(va, pb01, *op, 0, 0, 0);
            *op = __builtin_amdgcn_mfma_f32_16x16x32_bf16(vb, pb23, *op, 0, 0, 0);
        }
        __syncthreads();
    }

    // epilogue: reduce the deferred row-sum (lanes sharing l15), then
    // O^T regs -> LDS -> coalesced bf16 stores
    sm_l += __shfl_xor(sm_l, 16);
    sm_l += __shfl_xor(sm_l, 32);
    float* otw = (float*)smem + w * 16 * 68;
    float inv = 1.f / sm_l;
    #pragma unroll
    for (int r = 0; r < 4; ++r) {
        otw[l15*68 +  0 + quad*4 + r] = o0[r] * inv;
        otw[l15*68 + 16 + quad*4 + r] = o1[r] * inv;
        otw[l15*68 + 32 + quad*4 + r] = o2[r] * inv;
        otw[l15*68 + 48 + quad*4 + r] = o3[r] * inv;
    }
    asm volatile("s_waitcnt lgkmcnt(0)" ::: "memory");
    int row = lane >> 2, ch = (lane & 3) * 16;
    union { __bf16 hh[16]; uint4 q4[2]; } ob;
    #pragma unroll
    for (int t2 = 0; t2 < 16; ++t2) ob.hh[t2] = f2b(otw[row*68 + ch + t2]);
    __bf16* cp = qkc + (size_t)(b*SS + qrow0 + row) * 1024 + h*64 + ch;
    *(uint4*)cp = ob.q4[0];
    *(uint4*)(cp + 8) = ob.q4[1];
}

// ================= final projection (bf16 h) =================
__global__ __launch_bounds__(256) void proj_kernel(
    const __bf16* __restrict__ h_bf, const float* __restrict__ Wp,
    const float* __restrict__ bp, float* __restrict__ out)
{
    int rid = blockIdx.x * 8 + (threadIdx.x >> 5);
    int col = threadIdx.x & 31;
    int b = rid / TT, i = rid - b * TT;
    const __bf16* x = h_bf + ((size_t)(b*SS) + 3*i + 1) * HDIM;
    float acc = bp[col];
    for (int k8 = 0; k8 < HDIM/8; ++k8) {
        bf16x8 x8 = *(const bf16x8*)(x + k8*8);
        #pragma unroll
        for (int u = 0; u < 8; ++u)
            acc += (float)x8[u] * Wp[(k8*8 + u) * ADIM + col];
    }
    out[(size_t)rid * ADIM + col] = acc;
}

extern "C" void kernel_launch(void* const* d_in, const int* in_sizes, int n_in,
                              void* d_out, int out_size, void* d_ws, size_t ws_size,
                              hipStream_t stream)
{
    (void)in_sizes; (void)n_in; (void)out_size; (void)ws_size;
    const int*   timesteps = (const int*)  d_in[0];
    const float* state0    = (const float*)d_in[1];
    const float* state1    = (const float*)d_in[2];
    const float* actions   = (const float*)d_in[3];
    const float* time_emb  = (const float*)d_in[4];
    const float* Ws  = (const float*)d_in[5];
    const float* bs  = (const float*)d_in[6];
    const float* Wa  = (const float*)d_in[7];
    const float* ba  = (const float*)d_in[8];
    const float* Wq  = (const float*)d_in[9];
    const float* bq  = (const float*)d_in[10];
    const float* Wk  = (const float*)d_in[11];
    const float* bk  = (const float*)d_in[12];
    const float* Wv  = (const float*)d_in[13];
    const float* bv  = (const float*)d_in[14];
    const float* Wo  = (const float*)d_in[15];
    const float* bo  = (const float*)d_in[16];
    const float* W1  = (const float*)d_in[17];
    const float* b1  = (const float*)d_in[18];
    const float* W2  = (const float*)d_in[19];
    const float* b2  = (const float*)d_in[20];
    const float* ln1g = (const float*)d_in[21];
    const float* ln1b = (const float*)d_in[22];
    const float* ln2g = (const float*)d_in[23];
    const float* ln2b = (const float*)d_in[24];
    const float* elng = (const float*)d_in[25];
    const float* elnb = (const float*)d_in[26];
    const float* Wp   = (const float*)d_in[27];
    const float* bp   = (const float*)d_in[28];
    float* out = (float*)d_out;

    char* p = (char*)d_ws;
    __bf16* h_bf = (__bf16*)p;           p += SZE * 2;                  // residual (bf16)
    __bf16* qk   = (__bf16*)p;           p += (size_t)MS * 1024 * 2;   // q|k; q-sec doubles as ctx
    __bf16* VT   = (__bf16*)p;           p += SZE * 2;
    /* hid extension */                  p += SZE * 2;                  // hid = qk..VT..ext (MSx2048)
    __bf16* tmp  = (__bf16*)p;           p += SZE * 2 * 2;              // split-K partials 0..1
    __bf16* wqkvT = (__bf16*)p;          p += (size_t)NBLK * 1536 * 512 * 2;
    __bf16* woT   = (__bf16*)p;          p += (size_t)NBLK * 512 * 512 * 2;
    __bf16* w1T   = (__bf16*)p;          p += (size_t)NBLK * 2048 * 512 * 2;
    __bf16* w2T   = (__bf16*)p;          p += (size_t)NBLK * 512 * 2048 * 2;
    float*  biasq = (float*)p;           p += (size_t)NBLK * 1536 * 4;
    __bf16* hid   = qk;                  // MS x 2048 bf16 spans qk+VT+ext

    embed_ln_kernel<<<dim3(TT/8, 3, BB), 512, 0, stream>>>(timesteps, state0, state1, actions,
                                                           time_emb, Ws, bs, Wa, ba, elng, elnb, h_bf);

    // pack all 6 layers in one launch
    pack_kernel<<<dim3(769, NBLK), 256, 0, stream>>>(Wq, Wk, Wv, Wo, W1, W2, bq, bk, bv,
                                                     wqkvT, woT, w1T, w2T, biasq);

    dim3 gQKV(1536/128, MS/64, 1);     // 12 x 96  (MT=64, BK=32, 4.5 blocks/CU)
    dim3 gO  (512/128,  MS/64, 2);     // 4 x 96 x 2  (split-K=2, MT=64, BK=64, 3/CU)
    dim3 gF1 (2048/128, MS/64, 1);     // 16 x 96  (MT=64, BK=32, 6 blocks/CU)

    for (int lyr = 0; lyr < NBLK; ++lyr) {
        const __bf16* wqkvT_l = wqkvT + (size_t)lyr * 1536 * 512;
        const __bf16* woT_l   = woT   + (size_t)lyr * 512 * 512;
        const __bf16* w1T_l   = w1T   + (size_t)lyr * 2048 * 512;
        const __bf16* w2T_l   = w2T   + (size_t)lyr * 512 * 2048;
        const float*  biasq_l = biasq + (size_t)lyr * 1536;

        // QKV: q|k rows -> qk (ldc 1024); V tiles transposed -> VT in-epilogue
        gemm_mfma<64, 32, true><<<gQKV, 256, 0, stream>>>(h_bf, wqkvT_l, biasq_l, qk, VT,
                                                          1536, 512, 512, 512, 1024, 0, 0);
        attn_kernel<<<dim3(768), 256, 0, stream>>>(qk, VT);
        // WO: A = ctx (q-section, lda 1024); split-K=2 (256 each), BK=64 -> NK=4
        gemm_mfma<64, 64, false><<<gO, 256, 0, stream>>>(qk, woT_l, bo + lyr*HDIM, tmp, nullptr,
                                                         512, 256, 1024, 512, 512, 0, SZE);
        ln_add_kernel<2><<<MS/4, 256, 0, stream>>>(h_bf, tmp,
                                                   ln1g + lyr*HDIM, ln1b + lyr*HDIM);
        gemm_mfma<64, 32, false><<<gF1, 256, 0, stream>>>(h_bf, w1T_l, b1 + lyr*DFF, hid, nullptr,
                                                          2048, 512, 512, 512, 2048, 1, 0);
        // W2: split-K=2 (1024 each), MT=64, BK=64 -> NK=16 (was 32)
        gemm_mfma<64, 64, false><<<gO, 256, 0, stream>>>(hid, w2T_l, b2 + lyr*HDIM, tmp, nullptr,
                                                         512, 1024, 2048, 2048, 512, 0, SZE);
        ln_add_kernel<2><<<MS/4, 256, 0, stream>>>(h_bf, tmp,
                                                   ln2g + lyr*HDIM, ln2b + lyr*HDIM);
    }

    proj_kernel<<<(BB*TT)/8, 256, 0, stream>>>(h_bf, Wp, bp, out);
}

// Round 9
// 837.929 us; speedup vs baseline: 1.2051x; 1.0839x over previous
//
#include <hip/hip_runtime.h>
#include <hip/hip_bf16.h>
#include <math.h>

#define BB 4
#define TT 512
#define SDIM 64
#define ADIM 32
#define HDIM 512
#define NH 8
#define NBLK 6
#define DFF 2048
#define SS 1536          // 3*T
#define DH 64
#define MS (BB*SS)       // 6144 rows
#define SZE ((size_t)MS * HDIM)   // elements in one [MS][HDIM] partial

typedef __attribute__((ext_vector_type(8))) __bf16 bf16x8;
typedef __attribute__((ext_vector_type(4))) float f32x4;

__device__ __forceinline__ __bf16 f2b(float x) { return (__bf16)x; }

// async global->LDS, 16 B per lane; LDS dest = wave-uniform base + lane*16
__device__ __forceinline__ void gll16(const void* g, void* l) {
    __builtin_amdgcn_global_load_lds(
        (const __attribute__((address_space(1))) unsigned int*)g,
        (__attribute__((address_space(3))) unsigned int*)l, 16, 0, 0);
}

// ================= embed + LN -> h_bf (bf16 residual stream) =================
// 8 rows of the SAME type per block: W read once from L2 per 8 rows.
// grid (64, 3, 4): chunk, type t, batch b. 512 threads.
__global__ __launch_bounds__(512) void embed_ln_kernel(
    const int* __restrict__ timesteps,
    const float* __restrict__ state0, const float* __restrict__ state1,
    const float* __restrict__ actions, const float* __restrict__ time_emb,
    const float* __restrict__ Ws, const float* __restrict__ bs,
    const float* __restrict__ Wa, const float* __restrict__ ba,
    const float* __restrict__ eg, const float* __restrict__ eb,
    __bf16* __restrict__ h_bf)
{
    __shared__ float xs[8][64];
    __shared__ float acc_s[8][512];
    __shared__ int tss[8];
    int c = blockIdx.x, t = blockIdx.y, b = blockIdx.z;
    int i0 = c * 8;
    int tid = threadIdx.x;
    int K = (t == 2) ? ADIM : SDIM;
    int ksh = (t == 2) ? 5 : 6;
    const float* W    = (t == 2) ? Wa : Ws;
    const float* bias = (t == 2) ? ba : bs;
    const float* src  = (t == 0) ? state0  + ((size_t)(b*TT + i0)) * SDIM
                      : (t == 1) ? state1  + ((size_t)(b*TT + i0)) * SDIM
                                 : actions + ((size_t)(b*TT + i0)) * ADIM;

    if (tid < 8) tss[tid] = timesteps[b*TT + i0 + tid];
    for (int idx = tid; idx < 8 * K; idx += 512) {
        int r = idx >> ksh, kk = idx & (K - 1);
        xs[r][kk] = src[r * K + kk];           // row stride == K, contiguous
    }
    __syncthreads();

    float acc[8];
    #pragma unroll
    for (int r = 0; r < 8; ++r)
        acc[r] = bias[tid] + time_emb[(size_t)tss[r] * HDIM + tid];
    for (int kk = 0; kk < K; ++kk) {
        float w = W[(size_t)kk * HDIM + tid];
        #pragma unroll
        for (int r = 0; r < 8; ++r) acc[r] += xs[r][kk] * w;
    }
    #pragma unroll
    for (int r = 0; r < 8; ++r) acc_s[r][tid] = acc[r];
    __syncthreads();

    // wave w owns row w: vector read, shuffle-only LN, 16B store
    int w = tid >> 6, lane = tid & 63;
    float4 p0 = *(const float4*)&acc_s[w][lane * 8];
    float4 p1 = *(const float4*)&acc_s[w][lane * 8 + 4];
    float v[8] = {p0.x, p0.y, p0.z, p0.w, p1.x, p1.y, p1.z, p1.w};
    float s = 0.f, sq = 0.f;
    #pragma unroll
    for (int u = 0; u < 8; ++u) { s += v[u]; sq += v[u] * v[u]; }
    #pragma unroll
    for (int off = 1; off < 64; off <<= 1) { s += __shfl_xor(s, off); sq += __shfl_xor(sq, off); }
    float mean = s * (1.f / HDIM);
    float var  = sq * (1.f / HDIM) - mean * mean;
    float inv  = rsqrtf(var + 1e-5f);
    float4 g0 = *(const float4*)(eg + lane * 8), g1 = *(const float4*)(eg + lane * 8 + 4);
    float4 b0 = *(const float4*)(eb + lane * 8), b1 = *(const float4*)(eb + lane * 8 + 4);
    float gg[8] = {g0.x, g0.y, g0.z, g0.w, g1.x, g1.y, g1.z, g1.w};
    float bbv[8] = {b0.x, b0.y, b0.z, b0.w, b1.x, b1.y, b1.z, b1.w};
    __bf16 o8[8];
    #pragma unroll
    for (int u = 0; u < 8; ++u) o8[u] = f2b((v[u] - mean) * inv * gg[u] + bbv[u]);
    int row = b * SS + (i0 + w) * 3 + t;
    *(uint4*)(h_bf + (size_t)row * HDIM + lane * 8) = *(uint4*)o8;
}

// ================= residual add (NP bf16 partials, SZE-strided) + LN =================
// wave-per-row: bf16x8 loads, shuffle-only reduction, no barriers.
// grid MS/4 = 1536 blocks x 256 threads.
template<int NP>
__global__ __launch_bounds__(256) void ln_add_kernel(
    __bf16* __restrict__ h_bf, const __bf16* __restrict__ parts,
    const float* __restrict__ g, const float* __restrict__ bvec)
{
    int w = threadIdx.x >> 6, lane = threadIdx.x & 63;
    int row = blockIdx.x * 4 + w;
    size_t base = (size_t)row * HDIM + lane * 8;
    bf16x8 h8 = *(const bf16x8*)(h_bf + base);
    bf16x8 p8[NP];
    #pragma unroll
    for (int p = 0; p < NP; ++p) p8[p] = *(const bf16x8*)(parts + p * SZE + base);
    float v[8], s = 0.f, sq = 0.f;
    #pragma unroll
    for (int u = 0; u < 8; ++u) {
        float acc = (float)h8[u];
        #pragma unroll
        for (int p = 0; p < NP; ++p) acc += (float)p8[p][u];
        v[u] = acc;
        s += acc; sq += acc * acc;
    }
    #pragma unroll
    for (int off = 1; off < 64; off <<= 1) { s += __shfl_xor(s, off); sq += __shfl_xor(sq, off); }
    float mean = s * (1.f / HDIM);
    float var  = sq * (1.f / HDIM) - mean * mean;
    float inv  = rsqrtf(var + 1e-5f);
    float4 g0 = *(const float4*)(g + lane * 8), g1 = *(const float4*)(g + lane * 8 + 4);
    float4 b0 = *(const float4*)(bvec + lane * 8), b1 = *(const float4*)(bvec + lane * 8 + 4);
    float gg[8] = {g0.x, g0.y, g0.z, g0.w, g1.x, g1.y, g1.z, g1.w};
    float bbv[8] = {b0.x, b0.y, b0.z, b0.w, b1.x, b1.y, b1.z, b1.w};
    __bf16 o8[8];
    #pragma unroll
    for (int u = 0; u < 8; ++u) o8[u] = f2b((v[u] - mean) * inv * gg[u] + bbv[u]);
    *(uint4*)(h_bf + base) = *(uint4*)o8;
}

// ================= weight pack: fp32 [K][N] -> bf16 [N][K], all 6 layers =================
// grid (769, 6): blockIdx.y = layer.
__global__ __launch_bounds__(256) void pack_kernel(
    const float* __restrict__ Wq, const float* __restrict__ Wk,
    const float* __restrict__ Wv, const float* __restrict__ Wo,
    const float* __restrict__ W1, const float* __restrict__ W2,
    const float* __restrict__ bq_, const float* __restrict__ bk_, const float* __restrict__ bv_,
    __bf16* __restrict__ wqkvT, __bf16* __restrict__ woT,
    __bf16* __restrict__ w1T, __bf16* __restrict__ w2T, float* __restrict__ biasq)
{
    int lyr = blockIdx.y;
    const float* wq = Wq + (size_t)lyr * HDIM * HDIM;
    const float* wk = Wk + (size_t)lyr * HDIM * HDIM;
    const float* wv = Wv + (size_t)lyr * HDIM * HDIM;
    const float* wo = Wo + (size_t)lyr * HDIM * HDIM;
    const float* w1 = W1 + (size_t)lyr * HDIM * DFF;
    const float* w2 = W2 + (size_t)lyr * DFF * HDIM;
    const float* bqL = bq_ + (size_t)lyr * HDIM;
    const float* bkL = bk_ + (size_t)lyr * HDIM;
    const float* bvL = bv_ + (size_t)lyr * HDIM;
    wqkvT += (size_t)lyr * 1536 * 512;
    woT   += (size_t)lyr * 512 * 512;
    w1T   += (size_t)lyr * 2048 * 512;
    w2T   += (size_t)lyr * 512 * 2048;
    biasq += (size_t)lyr * 1536;

    int bid = blockIdx.x;
    int tid = threadIdx.x;
    if (bid == 768) {
        for (int i = tid; i < 1536; i += 256)
            biasq[i] = (i < 512) ? bqL[i] : ((i < 1024) ? bkL[i-512] : bvL[i-1024]);
        return;
    }
    __shared__ float Ls[64][65];
    const float* src; __bf16* dst; int K, N, kt, nt;
    if (bid < 192) {
        int sec = bid / 64, t = bid % 64;
        src = (sec == 0) ? wq : (sec == 1) ? wk : wv;
        dst = wqkvT + (size_t)sec * 512 * 512;
        K = 512; N = 512; nt = t >> 3; kt = t & 7;
    } else if (bid < 256) {
        int t = bid - 192; src = wo; dst = woT; K = 512; N = 512; nt = t >> 3; kt = t & 7;
    } else if (bid < 512) {
        int t = bid - 256; src = w1; dst = w1T; K = 512; N = 2048; nt = t >> 3; kt = t & 7;
    } else {
        int t = bid - 512; src = w2; dst = w2T; K = 2048; N = 512; nt = t & 7; kt = t >> 3;
    }
    int k0 = kt * 64, n0 = nt * 64;
    int rr = tid >> 4, cc = (tid & 15) * 4;
    #pragma unroll
    for (int p = 0; p < 4; ++p) {
        float4 v = *(const float4*)(src + (size_t)(k0 + rr + p*16) * N + n0 + cc);
        Ls[rr + p*16][cc] = v.x; Ls[rr + p*16][cc+1] = v.y;
        Ls[rr + p*16][cc+2] = v.z; Ls[rr + p*16][cc+3] = v.w;
    }
    __syncthreads();
    int nn = tid >> 3, kc = (tid & 7) * 8;
    #pragma unroll
    for (int p = 0; p < 2; ++p) {
        __bf16 t8[8];
        #pragma unroll
        for (int t2 = 0; t2 < 8; ++t2) t8[t2] = f2b(Ls[kc + t2][nn + p*32]);
        *(uint4*)(dst + (size_t)(n0 + nn + p*32) * K + k0 + kc) = *(uint4*)t8;
    }
}

// ================= bf16 MFMA GEMM, double-buffered async LDS staging =================
// Round-8 proven structure: 2 buffers, one __syncthreads per K-step,
// prefetch kt+1 inside the loop, direct C-write.
// BK = K-tile width (32 or 64). BK=64 halves the barrier count at the same
// 3-blocks/CU residency (use only where grid is a multiple of 768).
// XCD-aware tile remap: same-XCD blocks (b%8) share a disjoint 12-row
// A-band + the weight panels (<3 MB, fits the 4 MB per-XCD L2) -> A-panels
// fetched once per XCD instead of ~8x from L3. Bijective, correctness-free.
// A: bf16 [M][lda].  Bt: bf16 [N][ldb].  C: bf16 [M][ldc].
// Split-K via blockIdx.z; bias applied only on z==0.
// VTMODE: blocks with n0 >= 1024 write their tile TRANSPOSED to VTout.
template<int MT, int BK, bool VTMODE>
__global__ __launch_bounds__(256) void gemm_mfma(
    const __bf16* __restrict__ A, const __bf16* __restrict__ Bt,
    const float* __restrict__ bias, __bf16* __restrict__ C,
    __bf16* __restrict__ VTout,
    int N, int Ksub, int lda, int ldb, int ldc, int gelu, size_t cSplitStride)
{
    constexpr int MI = MT / 32;
    constexpr int KC = BK / 32;                  // 32-wide k-chunks per step
    constexpr int CH = BK / 8;                   // 8-elem chunks per row
    constexpr int RPC = 64 / CH;                 // rows per wave-call
    constexpr int SMB = 2*MT*BK*2 + 2*128*BK*2;
    __shared__ __align__(16) char sm[SMB];
    __bf16* As = (__bf16*)sm;                    // [2][MT][BK]
    __bf16* Bs = (__bf16*)(sm + 2*MT*BK*2);      // [2][128][BK]
    int tid = threadIdx.x;
    int wave = tid >> 6, lane = tid & 63;
    int l15 = lane & 15, quad = lane >> 4;
    int wy = wave >> 1, wx = wave & 1;

    // XCD-aware remap (bijective; gridDim.y must be divisible by 8)
    int bx = blockIdx.x, by = blockIdx.y;
    if ((gridDim.y & 7) == 0) {
        int yb = gridDim.y >> 3;
        int b = bx + gridDim.x * by;
        int c = b & 7, j = b >> 3;
        by = c * yb + j % yb;
        bx = j / yb;
    }
    int m0 = by * MT, n0 = bx * 128;
    int zs = blockIdx.z;
    int kbase = zs * Ksub;
    C += (size_t)zs * cSplitStride;

    int srow, clog;
    if (BK == 32) { srow = lane >> 2; clog = (lane & 3) ^ ((lane >> 3) & 3); }
    else          { srow = lane >> 3; clog = (lane & 7) ^ ((lane >> 3) & 7); }

    f32x4 acc[MI][4];
    #pragma unroll
    for (int i = 0; i < MI; ++i)
        #pragma unroll
        for (int j = 0; j < 4; ++j) acc[i][j] = (f32x4){0.f,0.f,0.f,0.f};

    const __bf16* Abase = A  + (size_t)m0 * lda + kbase + clog * 8;
    const __bf16* Bbase = Bt + (size_t)n0 * ldb + kbase + clog * 8;
    int NK = Ksub / BK;

    constexpr int ACALLS = MT / (4 * RPC);       // per wave
    constexpr int BCALLS = 128 / (4 * RPC);

    // prologue: stage k-tile 0 into buffer 0
    #pragma unroll
    for (int q = 0; q < ACALLS; ++q) {
        int r0 = (wave * ACALLS + q) * RPC;
        gll16(Abase + (size_t)(r0 + srow) * lda, As + r0*BK);
    }
    #pragma unroll
    for (int q = 0; q < BCALLS; ++q) {
        int r0 = (wave * BCALLS + q) * RPC;
        gll16(Bbase + (size_t)(r0 + srow) * ldb, Bs + r0*BK);
    }

    for (int kt = 0; kt < NK; ++kt) {
        int buf = kt & 1;
        __syncthreads();   // drains the loads for `buf` (issued one full iter ago)
        if (kt + 1 < NK) {
            int k0 = (kt + 1) * BK;
            #pragma unroll
            for (int q = 0; q < ACALLS; ++q) {
                int r0 = (wave * ACALLS + q) * RPC;
                gll16(Abase + (size_t)(r0 + srow) * lda + k0, As + ((buf^1)*MT + r0)*BK);
            }
            #pragma unroll
            for (int q = 0; q < BCALLS; ++q) {
                int r0 = (wave * BCALLS + q) * RPC;
                gll16(Bbase + (size_t)(r0 + srow) * ldb + k0, Bs + ((buf^1)*128 + r0)*BK);
            }
        }
        bf16x8 af[KC][MI], bf[KC][4];
        #pragma unroll
        for (int kk = 0; kk < KC; ++kk) {
            int pch;
            if (BK == 32) pch = (quad ^ ((l15 >> 1) & 3)) * 8;
            else          pch = ((kk*4 + quad) ^ (l15 & 7)) * 8;
            #pragma unroll
            for (int i = 0; i < MI; ++i)
                af[kk][i] = *(const bf16x8*)&As[(buf*MT + wy*(MT/2) + i*16 + l15)*BK + pch];
            #pragma unroll
            for (int j = 0; j < 4; ++j)
                bf[kk][j] = *(const bf16x8*)&Bs[(buf*128 + wx*64 + j*16 + l15)*BK + pch];
        }
        #pragma unroll
        for (int kk = 0; kk < KC; ++kk)
            #pragma unroll
            for (int i = 0; i < MI; ++i)
                #pragma unroll
                for (int j = 0; j < 4; ++j)
                    acc[i][j] = __builtin_amdgcn_mfma_f32_16x16x32_bf16(af[kk][i], bf[kk][j], acc[i][j], 0, 0, 0);
    }

    if (VTMODE && n0 >= 1024) {
        // transpose tile (MT s x 128 d) into VT via LDS (reuse staging)
        constexpr int SCH = MT / 4;       // s-chunks of 4
        __syncthreads();
        __bf16* T = (__bf16*)sm;          // logical [128 d][MT s], s-chunk swizzled
        #pragma unroll
        for (int j = 0; j < 4; ++j) {
            int dl = wx*64 + j*16 + l15;
            float bv = bias[n0 + dl];
            int xm = dl & (SCH - 1);
            #pragma unroll
            for (int i = 0; i < MI; ++i) {
                int sc = wy*(MI*4) + i*4 + quad;      // 4-elem s-chunk index
                int phys = sc ^ xm;
                __bf16 v4[4];
                #pragma unroll
                for (int r = 0; r < 4; ++r) v4[r] = f2b(acc[i][j][r] + bv);
                *(uint2*)(T + dl*MT + phys*4) = *(uint2*)v4;
            }
        }
        __syncthreads();
        constexpr int SPT = MT / 2;       // s per thread (2 threads per d row)
        int dl = tid >> 1, sh = (tid & 1) * SPT;
        int dglob = n0 - 1024 + dl;
        int bb = m0 / SS, srel = m0 - bb*SS;
        __bf16* vb = VTout + ((size_t)(bb*NH + (dglob >> 6)) * 64 + (dglob & 63)) * SS + srel + sh;
        int xm = dl & (SCH - 1);
        #pragma unroll
        for (int u = 0; u < SPT/8; ++u) {
            int c0 = (sh >> 2) + u*2;
            uint2 lo = *(const uint2*)(T + dl*MT + ((c0    ) ^ xm)*4);
            uint2 hi = *(const uint2*)(T + dl*MT + ((c0 + 1) ^ xm)*4);
            uint4 o; o.x = lo.x; o.y = lo.y; o.z = hi.x; o.w = hi.y;
            *(uint4*)(vb + u*8) = o;
        }
        return;
    }

    #pragma unroll
    for (int j = 0; j < 4; ++j) {
        int cc = n0 + wx*64 + j*16 + l15;
        float bv = (zs == 0) ? bias[cc] : 0.f;
        #pragma unroll
        for (int i = 0; i < MI; ++i) {
            #pragma unroll
            for (int r = 0; r < 4; ++r) {
                int rr = m0 + wy*(MT/2) + i*16 + quad*4 + r;
                float v = acc[i][j][r] + bv;
                if (gelu) {
                    // tanh-form GELU via exp2+rcp (~7 VALU ops vs ~35 for erff;
                    // |err| <= ~3e-4 on gelu output, far below bf16 rounding)
                    float u2 = v * (0.7978845608f + 0.0356774081f * v * v);
                    float e  = __builtin_amdgcn_exp2f(u2 * 2.885390082f);  // exp(2u)
                    v = v * (1.f - __builtin_amdgcn_rcpf(e + 1.f));        // v*sigmoid(2u)
                }
                C[(size_t)rr * ldc + cc] = f2b(v);
            }
        }
    }
}

// ================= S^T-layout MFMA flash attention, 64-row K-tiles =================
#define SM_C 0.18033688011112042f   // (1/8) * log2(e)

__device__ __forceinline__ unsigned pack2bf(float a, float b)
{
    union { __bf16 h[2]; unsigned u; } t;
    t.h[0] = (__bf16)a; t.h[1] = (__bf16)b;
    return t.u;
}

// P^T (two 16-row frags) -> PV B-frag. All shuffles at full wave exec,
// per-lane cndmask after (verified in rounds 4-10).
__device__ __forceinline__ bf16x8 ptrans(const float* p0, const float* p1, int lane)
{
    int l15 = lane & 15, quad = lane >> 4;
    unsigned pk0a = pack2bf(p0[0], p0[1]), pk0b = pack2bf(p0[2], p0[3]);
    unsigned pk1a = pack2bf(p1[0], p1[1]), pk1b = pack2bf(p1[2], p1[3]);
    int sA = l15 + (quad & 1) * 32;
    int sB = sA + 16;
    int hi = quad >> 1;
    unsigned a0A = (unsigned)__shfl((int)pk0a, sA);
    unsigned a1A = (unsigned)__shfl((int)pk1a, sA);
    unsigned b0A = (unsigned)__shfl((int)pk0b, sA);
    unsigned b1A = (unsigned)__shfl((int)pk1b, sA);
    unsigned a0B = (unsigned)__shfl((int)pk0a, sB);
    unsigned a1B = (unsigned)__shfl((int)pk1a, sB);
    unsigned b0B = (unsigned)__shfl((int)pk0b, sB);
    unsigned b1B = (unsigned)__shfl((int)pk1b, sB);
    union { unsigned u[4]; bf16x8 v; } pb;
    pb.u[0] = hi ? a1A : a0A;
    pb.u[1] = hi ? b1A : b0A;
    pb.u[2] = hi ? a1B : a0B;
    pb.u[3] = hi ? b1B : b0B;
    return pb.v;
}

// grid: 768 blocks (region-interleaved qt, LONGEST FIRST), 256 threads.
// qkc: [row][1024] = q|k; ctx overwrites the q-section (disjoint ownership).
// LDS (32 KB): K tile [64 s][64 d] x2 bufs, V^T tile [64 d][64 s] x2,
// chunk-swizzled phys = c ^ (row & 7). nkt = qt+1, uniform across waves.
// Softmax uses a TILE-WIDE max (wave-uniform sm_m) => sm_l is kept as a
// per-lane partial and reduced once in the epilogue; the per-tile max
// reduce happens only inside the (rare) rescale branch.
__global__ __launch_bounds__(256, 3) void attn_kernel(
    __bf16* qkc, const __bf16* __restrict__ VT)
{
    __shared__ __align__(16) char smem[32768];

    int x = blockIdx.x;
    int region = x >> 8;          // 0,1,2
    int j = x & 255;
    int i = j >> 5;               // 0..7
    int hb = j & 31;
    // longest blocks dispatched first to shrink the tail
    int qt = (region == 0) ? (23 - i) : (region == 1) ? (8 + i) : i;
    int h = hb >> 2, b = hb & 3;

    int tid = threadIdx.x;
    int w = tid >> 6, lane = tid & 63;
    int l15 = lane & 15, quad = lane >> 4;
    int qrow0 = qt * 64 + w * 16;

    const __bf16* qp = qkc + (size_t)(b*SS + qrow0 + l15) * 1024 + h*64 + quad*8;
    bf16x8 qf0 = *(const bf16x8*)qp;
    bf16x8 qf1 = *(const bf16x8*)(qp + 32);

    // staging bases
    const __bf16* kgbase = qkc + (size_t)(b*SS) * 1024 + 512 + h*64;     // + srow*1024
    const __bf16* vgbase = VT + (size_t)(b*NH + h) * 64 * SS;            // + drow*SS
    int srow8 = lane >> 3;                        // 0..7
    int clog  = (lane & 7) ^ ((lane >> 3) & 7);   // logical chunk for DMA lane
    int sw0 = ((0*4 + quad) ^ (l15 & 7)) * 8;
    int sw1 = ((1*4 + quad) ^ (l15 & 7)) * 8;

    f32x4 o0 = {0.f,0.f,0.f,0.f}, o1 = o0, o2 = o0, o3 = o0;
    float sm_m = -1e30f, sm_l = 0.f;   // sm_l: PER-LANE partial (reduced at end)

    int nkt = qt + 1;

    #pragma unroll
    for (int q = 0; q < 2; ++q) {
        int r0 = (w*2 + q) * 8;
        gll16(kgbase + (size_t)(r0 + srow8) * 1024 + clog*8, (__bf16*)smem + r0*64);
        gll16(vgbase + (size_t)(r0 + srow8) * SS   + clog*8, (__bf16*)(smem + 16384) + r0*64);
    }
    __syncthreads();

    for (int jt = 0; jt < nkt; ++jt) {
        int buf = jt & 1;
        const __bf16* Kb = (const __bf16*)(smem + buf * 8192);
        const __bf16* Vb = (const __bf16*)(smem + 16384 + buf * 8192);
        if (jt + 1 < nkt) {
            int kb2 = (jt + 1) * 64;
            __bf16* Kn = (__bf16*)(smem + (buf ^ 1) * 8192);
            __bf16* Vn = (__bf16*)(smem + 16384 + (buf ^ 1) * 8192);
            #pragma unroll
            for (int q = 0; q < 2; ++q) {
                int r0 = (w*2 + q) * 8;
                gll16(kgbase + (size_t)(kb2 + r0 + srow8) * 1024 + clog*8, Kn + r0*64);
                gll16(vgbase + (size_t)(r0 + srow8) * SS + kb2 + clog*8,   Vn + r0*64);
            }
        }
        int kb = jt * 64;

        f32x4 s[4];
        #pragma unroll
        for (int f = 0; f < 4; ++f) {
            bf16x8 k0 = *(const bf16x8*)(Kb + (16*f + l15)*64 + sw0);
            bf16x8 k1 = *(const bf16x8*)(Kb + (16*f + l15)*64 + sw1);
            f32x4 sf = {0.f,0.f,0.f,0.f};
            sf = __builtin_amdgcn_mfma_f32_16x16x32_bf16(k0, qf0, sf, 0, 0, 0);
            sf = __builtin_amdgcn_mfma_f32_16x16x32_bf16(k1, qf1, sf, 0, 0, 0);
            s[f] = sf;
        }

        if (kb + 63 > qrow0) {
            int qrow = qrow0 + l15;
            #pragma unroll
            for (int f = 0; f < 4; ++f)
                #pragma unroll
                for (int r = 0; r < 4; ++r)
                    if (kb + 16*f + quad*4 + r > qrow) s[f][r] = -1e30f;
        }

        // per-lane tree max (no cross-lane traffic on the common path)
        float tf[4];
        #pragma unroll
        for (int f = 0; f < 4; ++f)
            tf[f] = fmaxf(fmaxf(s[f][0], s[f][1]), fmaxf(s[f][2], s[f][3]));
        float tm_lane = fmaxf(fmaxf(tf[0], tf[1]), fmaxf(tf[2], tf[3]));

        // defer-max (T13): rescale only if some lane's max grows past
        // sm_m + 64 raw-score units (=> P <= e^8, safe in fp32/bf16).
        if (!__all(tm_lane <= sm_m + 64.f)) {
            float tm = tm_lane;
            tm = fmaxf(tm, __shfl_xor(tm, 16));
            tm = fmaxf(tm, __shfl_xor(tm, 32));
            float mnew = fmaxf(sm_m, tm);
            float alpha = __builtin_amdgcn_exp2f((sm_m - mnew) * SM_C);  // uniform
            sm_l *= alpha;
            o0 *= alpha; o1 *= alpha; o2 *= alpha; o3 *= alpha;
            sm_m = mnew;
        }

        // p = exp2(s*C - m*C): one fma + one exp2 per element
        float negmC = -sm_m * SM_C;
        float pp[4][4];
        float rf[4];
        #pragma unroll
        for (int f = 0; f < 4; ++f) {
            #pragma unroll
            for (int r = 0; r < 4; ++r)
                pp[f][r] = __builtin_amdgcn_exp2f(fmaf(s[f][r], SM_C, negmC));
            rf[f] = (pp[f][0] + pp[f][1]) + (pp[f][2] + pp[f][3]);
        }
        sm_l += (rf[0] + rf[1]) + (rf[2] + rf[3]);   // per-lane partial only

        bf16x8 pb01 = ptrans(pp[0], pp[1], lane);
        bf16x8 pb23 = ptrans(pp[2], pp[3], lane);

        #pragma unroll
        for (int ii = 0; ii < 4; ++ii) {
            bf16x8 va = *(const bf16x8*)(Vb + (16*ii + l15)*64 + sw0);
            bf16x8 vb = *(const bf16x8*)(Vb + (16*ii + l15)*64 + sw1);
            f32x4* op = (ii == 0) ? &o0 : (ii == 1) ? &o1 : (ii == 2) ? &o2 : &o3;
            *op = __builtin_amdgcn_mfma_f32_16x16x32_bf16(va, pb01, *op, 0, 0, 0);
            *op = __builtin_amdgcn_mfma_f32_16x16x32_bf16(vb, pb23, *op, 0, 0, 0);
        }
        __syncthreads();
    }

    // epilogue: reduce the deferred row-sum (lanes sharing l15), then
    // O^T regs -> LDS -> coalesced bf16 stores
    sm_l += __shfl_xor(sm_l, 16);
    sm_l += __shfl_xor(sm_l, 32);
    float* otw = (float*)smem + w * 16 * 68;
    float inv = 1.f / sm_l;
    #pragma unroll
    for (int r = 0; r < 4; ++r) {
        otw[l15*68 +  0 + quad*4 + r] = o0[r] * inv;
        otw[l15*68 + 16 + quad*4 + r] = o1[r] * inv;
        otw[l15*68 + 32 + quad*4 + r] = o2[r] * inv;
        otw[l15*68 + 48 + quad*4 + r] = o3[r] * inv;
    }
    asm volatile("s_waitcnt lgkmcnt(0)" ::: "memory");
    int row = lane >> 2, ch = (lane & 3) * 16;
    union { __bf16 hh[16]; uint4 q4[2]; } ob;
    #pragma unroll
    for (int t2 = 0; t2 < 16; ++t2) ob.hh[t2] = f2b(otw[row*68 + ch + t2]);
    __bf16* cp = qkc + (size_t)(b*SS + qrow0 + row) * 1024 + h*64 + ch;
    *(uint4*)cp = ob.q4[0];
    *(uint4*)(cp + 8) = ob.q4[1];
}

// ================= final projection (bf16 h) =================
__global__ __launch_bounds__(256) void proj_kernel(
    const __bf16* __restrict__ h_bf, const float* __restrict__ Wp,
    const float* __restrict__ bp, float* __restrict__ out)
{
    int rid = blockIdx.x * 8 + (threadIdx.x >> 5);
    int col = threadIdx.x & 31;
    int b = rid / TT, i = rid - b * TT;
    const __bf16* x = h_bf + ((size_t)(b*SS) + 3*i + 1) * HDIM;
    float acc = bp[col];
    for (int k8 = 0; k8 < HDIM/8; ++k8) {
        bf16x8 x8 = *(const bf16x8*)(x + k8*8);
        #pragma unroll
        for (int u = 0; u < 8; ++u)
            acc += (float)x8[u] * Wp[(k8*8 + u) * ADIM + col];
    }
    out[(size_t)rid * ADIM + col] = acc;
}

extern "C" void kernel_launch(void* const* d_in, const int* in_sizes, int n_in,
                              void* d_out, int out_size, void* d_ws, size_t ws_size,
                              hipStream_t stream)
{
    (void)in_sizes; (void)n_in; (void)out_size; (void)ws_size;
    const int*   timesteps = (const int*)  d_in[0];
    const float* state0    = (const float*)d_in[1];
    const float* state1    = (const float*)d_in[2];
    const float* actions   = (const float*)d_in[3];
    const float* time_emb  = (const float*)d_in[4];
    const float* Ws  = (const float*)d_in[5];
    const float* bs  = (const float*)d_in[6];
    const float* Wa  = (const float*)d_in[7];
    const float* ba  = (const float*)d_in[8];
    const float* Wq  = (const float*)d_in[9];
    const float* bq  = (const float*)d_in[10];
    const float* Wk  = (const float*)d_in[11];
    const float* bk  = (const float*)d_in[12];
    const float* Wv  = (const float*)d_in[13];
    const float* bv  = (const float*)d_in[14];
    const float* Wo  = (const float*)d_in[15];
    const float* bo  = (const float*)d_in[16];
    const float* W1  = (const float*)d_in[17];
    const float* b1  = (const float*)d_in[18];
    const float* W2  = (const float*)d_in[19];
    const float* b2  = (const float*)d_in[20];
    const float* ln1g = (const float*)d_in[21];
    const float* ln1b = (const float*)d_in[22];
    const float* ln2g = (const float*)d_in[23];
    const float* ln2b = (const float*)d_in[24];
    const float* elng = (const float*)d_in[25];
    const float* elnb = (const float*)d_in[26];
    const float* Wp   = (const float*)d_in[27];
    const float* bp   = (const float*)d_in[28];
    float* out = (float*)d_out;

    char* p = (char*)d_ws;
    __bf16* h_bf = (__bf16*)p;           p += SZE * 2;                  // residual (bf16)
    __bf16* qk   = (__bf16*)p;           p += (size_t)MS * 1024 * 2;   // q|k; q-sec doubles as ctx
    __bf16* VT   = (__bf16*)p;           p += SZE * 2;
    /* hid extension */                  p += SZE * 2;                  // hid = qk..VT..ext (MSx2048)
    __bf16* tmp  = (__bf16*)p;           p += SZE * 2 * 2;              // split-K partials 0..1
    __bf16* wqkvT = (__bf16*)p;          p += (size_t)NBLK * 1536 * 512 * 2;
    __bf16* woT   = (__bf16*)p;          p += (size_t)NBLK * 512 * 512 * 2;
    __bf16* w1T   = (__bf16*)p;          p += (size_t)NBLK * 2048 * 512 * 2;
    __bf16* w2T   = (__bf16*)p;          p += (size_t)NBLK * 512 * 2048 * 2;
    float*  biasq = (float*)p;           p += (size_t)NBLK * 1536 * 4;
    __bf16* hid   = qk;                  // MS x 2048 bf16 spans qk+VT+ext

    embed_ln_kernel<<<dim3(TT/8, 3, BB), 512, 0, stream>>>(timesteps, state0, state1, actions,
                                                           time_emb, Ws, bs, Wa, ba, elng, elnb, h_bf);

    // pack all 6 layers in one launch
    pack_kernel<<<dim3(769, NBLK), 256, 0, stream>>>(Wq, Wk, Wv, Wo, W1, W2, bq, bk, bv,
                                                     wqkvT, woT, w1T, w2T, biasq);

    dim3 gQKV(1536/128, MS/64, 1);     // 12 x 96  (MT=64, BK=32, 4.5 blocks/CU)
    dim3 gO  (512/128,  MS/64, 2);     // 4 x 96 x 2  (split-K=2, MT=64, BK=64, 3/CU)
    dim3 gF1 (2048/128, MS/64, 1);     // 16 x 96  (MT=64, BK=64, 3/CU, 2 clean waves)

    for (int lyr = 0; lyr < NBLK; ++lyr) {
        const __bf16* wqkvT_l = wqkvT + (size_t)lyr * 1536 * 512;
        const __bf16* woT_l   = woT   + (size_t)lyr * 512 * 512;
        const __bf16* w1T_l   = w1T   + (size_t)lyr * 2048 * 512;
        const __bf16* w2T_l   = w2T   + (size_t)lyr * 512 * 2048;
        const float*  biasq_l = biasq + (size_t)lyr * 1536;

        // QKV: q|k rows -> qk (ldc 1024); V tiles transposed -> VT in-epilogue
        gemm_mfma<64, 32, true><<<gQKV, 256, 0, stream>>>(h_bf, wqkvT_l, biasq_l, qk, VT,
                                                          1536, 512, 512, 512, 1024, 0, 0);
        attn_kernel<<<dim3(768), 256, 0, stream>>>(qk, VT);
        // WO: A = ctx (q-section, lda 1024); split-K=2 (256 each), BK=64 -> NK=4
        gemm_mfma<64, 64, false><<<gO, 256, 0, stream>>>(qk, woT_l, bo + lyr*HDIM, tmp, nullptr,
                                                         512, 256, 1024, 512, 512, 0, SZE);
        ln_add_kernel<2><<<MS/4, 256, 0, stream>>>(h_bf, tmp,
                                                   ln1g + lyr*HDIM, ln1b + lyr*HDIM);
        // W1: BK=64 -> NK=8 (was 16), 48 KB LDS, 3/CU, 2 clean waves
        gemm_mfma<64, 64, false><<<gF1, 256, 0, stream>>>(h_bf, w1T_l, b1 + lyr*DFF, hid, nullptr,
                                                          2048, 512, 512, 512, 2048, 1, 0);
        // W2: split-K=2 (1024 each), MT=64, BK=64 -> NK=16
        gemm_mfma<64, 64, false><<<gO, 256, 0, stream>>>(hid, w2T_l, b2 + lyr*HDIM, tmp, nullptr,
                                                         512, 1024, 2048, 2048, 512, 0, SZE);
        ln_add_kernel<2><<<MS/4, 256, 0, stream>>>(h_bf, tmp,
                                                   ln2g + lyr*HDIM, ln2b + lyr*HDIM);
    }

    proj_kernel<<<(BB*TT)/8, 256, 0, stream>>>(h_bf, Wp, bp, out);
}